// Round 3
// baseline (212.922 us; speedup 1.0000x reference)
//
#include <hip/hip_runtime.h>
#include <math.h>

#define BB 4
#define HH 128
#define WW 128
#define HWP (HH*WW)
#define DIMC 48
#define HIDC 96
#define NSETC 32

// Odd-dword LDS row strides (bank-conflict fix):
#define XS_W 27     // xs row stride in dwords (was 26)
#define HS_W 102    // hsw row stride in ushorts = 51 dwords (was 100)
#define US_W 102    // us2p row stride in ushorts = 51 dwords (was 100)

typedef __attribute__((ext_vector_type(8))) short bf16x8;
typedef __attribute__((ext_vector_type(4))) float f32x4;
typedef __attribute__((ext_vector_type(2))) float f32x2;

static __device__ __forceinline__ unsigned short f2bf(float f) {   // RNE (pack path, cold)
    union { float f; unsigned u; } v; v.f = f;
    unsigned r = (v.u + 0x7FFFu + ((v.u >> 16) & 1u)) >> 16;
    return (unsigned short)r;
}
static __device__ __forceinline__ unsigned rnd_bf(float f) {       // +0x8000 round-half-up
    union { float f; unsigned u; } v; v.f = f;
    return v.u + 0x8000u;
}
static __device__ __forceinline__ unsigned pack2bf(float lo, float hi) {
    return __builtin_amdgcn_perm(rnd_bf(hi), rnd_bf(lo), 0x07060302u);
}
static __device__ __forceinline__ void st_bf_hi(unsigned short* p, float f) {
    *p = (unsigned short)(rnd_bf(f) >> 16);
}
static __device__ __forceinline__ float bf2f(unsigned short u) {
    union { unsigned u; float f; } v; v.u = ((unsigned)u) << 16;
    return v.f;
}
static __device__ __forceinline__ float bfpair_lo(unsigned pr) {
    union { unsigned u; float f; } v; v.u = pr << 16; return v.f;
}
static __device__ __forceinline__ float bfpair_hi(unsigned pr) {
    union { unsigned u; float f; } v; v.u = pr & 0xffff0000u; return v.f;
}
static __device__ __forceinline__ float gelu(float x) {
    return 0.5f * x * (1.0f + erff(x * 0.70710678118654752f));
}

// ---------------- K0: weight pack (permuted A-operand layouts) + x transpose ----------------
// blocks [0,300): pack ; blocks [300,556): xpose (256 px each); xblk 0 zeroes pooled.
__global__ __launch_bounds__(256) void k_prep(
    const float* __restrict__ x,
    const float* __restrict__ kbaw, const float* __restrict__ kbab,
    const float* __restrict__ dw1w, const float* __restrict__ c1w1,
    const float* __restrict__ ga1,  const float* __restrict__ c211w,
    const float* __restrict__ c2w2, const float* __restrict__ c2b2,
    const float* __restrict__ c211b, const float* __restrict__ attg,
    unsigned short* __restrict__ Bpk, unsigned short* __restrict__ Bpw,
    unsigned short* __restrict__ Aps, unsigned short* __restrict__ Ag,
    unsigned* __restrict__ x_p, float* __restrict__ pooled)
{
    __shared__ unsigned ts[256 * 26];
    int blk = blockIdx.x, tid = threadIdx.x;
    if (blk < 300) {
        int t = blk * 256 + tid;
        if (t < 61440) {                         // BpkA
            int j = t & 7, lane = (t >> 3) & 63, tile = t >> 9;
            int chunk = tile / 10, nt = tile - chunk * 10;
            int m = lane & 15, qn = lane >> 4;
            int lc = 4 * nt + (m & 3);           // local col within this q's 40-block
            int o = lc / 20, tt = lc % 20;
            int c = (m >> 2) * 24 + 2 * chunk + o;
            int n = qn * 8 + j;
            float v = 0.f;
            if (tt < 18)       v = kbaw[n * 1728 + (c >> 1) * 36 + (c & 1) * 18 + tt] * ga1[c];
            else if (tt == 18) v = kbab[n * 96 + c] * ga1[c];
            Bpk[t] = f2bf(v);
        } else if (t < 73728) {                  // Bpw (B operand, unchanged)
            int u = t - 61440;
            int s = u / 6144;
            int rem = u % 6144;
            int nt = rem >> 9;
            int lane = (rem >> 3) & 63, j = rem & 7;
            int k = s * 32 + ((lane >> 4) << 3) + j;
            int col = (nt << 4) + (lane & 15);
            float v = 0.f;
            if (k < 48) v = (col < 96) ? dw1w[col * 48 + k] : c1w1[(col - 96) * 48 + k];
            Bpw[u] = f2bf(v);
        } else if (t < 75776) {                  // Aps (skip 1x1 A-operand)
            int u = t - 73728;
            int j = u & 7, lane = (u >> 3) & 63, tile = u >> 9;   // 0..3 = kt*2+nt2
            int kt = tile >> 1, nt2 = tile & 1;
            int m = lane & 15, qn = lane >> 4;
            int n = 8 * (m >> 2) + 4 * nt2 + (m & 3);
            int k = kt * 32 + qn * 8 + j;
            Aps[u] = f2bf(k < 48 ? c211w[n * 48 + k] : 0.f);
        } else if (t < 76800) {                  // Ag (gate 1x1 A-operand, biases at k=12)
            int u = t - 75776;
            int j = u & 7, lane = (u >> 3) & 63, nt2 = u >> 9;    // 0..1
            int m = lane & 15, qn = lane >> 4;
            int n = 8 * (m >> 2) + 4 * nt2 + (m & 3);
            int k = qn * 8 + j;
            float v = 0.f;
            if (k < 12)       v = c2w2[n * 12 + k] * attg[n];
            else if (k == 12) v = c2b2[n] * attg[n] + c211b[n];
            Ag[u] = f2bf(v);
        }
    } else {
        int xblk = blk - 300;
        if (xblk == 0) {
            for (int i = tid; i < BB * HIDC; i += 256) pooled[i] = 0.f;
        }
        int b = xblk >> 6;
        int p0 = (xblk & 63) << 8;
        const float* xb = x + (size_t)b * DIMC * HWP + p0;
        #pragma unroll
        for (int c2 = 0; c2 < 24; ++c2) {
            float lo = xb[(2 * c2) * HWP + tid];
            float hi = xb[(2 * c2 + 1) * HWP + tid];
            ts[tid * 26 + c2] = pack2bf(lo, hi);
        }
        __syncthreads();
        unsigned* dst = x_p + ((size_t)b * HWP + p0) * 24;
        for (int idx = tid; idx < 256 * 24; idx += 256) {
            int px = idx / 24, j2 = idx - px * 24;
            dst[px * 24 + j2] = ts[px * 26 + j2];
        }
    }
}

// ---------------- K1 (mega-fused): att + 1x1 MFMA + depthwise + KBA -> comb(bf16) ----------------
// 1024 blocks, dim3(64,8); 2 blocks/CU (LDS ~69.5 KB) -> 4 waves/SIMD.
// Round-3 changes: (1) KBA BpkA stream explicitly double-buffered in VGPRs (prefetch chunk
// cl+1 during chunk cl compute) -- was limited to ~4 loads in flight at VGPR=64;
// (2) PASS A balanced: rg8's nt-tiles spread over waves 1-6 instead of wave0 doing 2 rgs.
__global__ __launch_bounds__(512, 4) void k_mff(
    const unsigned* __restrict__ x_p,
    const uint4* __restrict__ BpkA, const uint4* __restrict__ Bpw,
    const uint4* __restrict__ Aps,  const uint4* __restrict__ Ag,
    const float* __restrict__ c1w2, const float* __restrict__ dw2w,
    const float* __restrict__ c2w1, const float* __restrict__ c2b1,
    unsigned* __restrict__ comb_bf, float* __restrict__ pooled)
{
    __shared__ __attribute__((aligned(16))) unsigned xs[144 * XS_W];        // x halo 12x12, bf16 pairs (15.2 KB)
    __shared__ __attribute__((aligned(16))) unsigned short hsw[144 * HS_W]; // h tiles ; aliased att_t (28.7 KB)
    __shared__ unsigned short us2p[100 * US_W];                             // uf halo (19.9 KB)
    __shared__ float wls[864 + 432 + 24];                                   // dw2w | c2w1-relayout | c2b1 (5.3 KB)
    __shared__ float pooled_s[96];

    int lane = threadIdx.x, wy = threadIdx.y;   // wy 0..7
    int tid = wy * 64 + lane;
    int blk = blockIdx.x;
    int b = blk >> 8, ty = (blk >> 4) & 15, tx = blk & 15;
    int q = lane >> 4, i16 = lane & 15;
    int wh = wy >> 2;          // channel/chunk half (0/1)
    int wp = wy & 3;           // pixel group 0..3

    float* wats  = wls + 864;    // [g][tap][2]
    float* c2b1s = wls + 864 + 432;
    float* att_tf = (float*)hsw; // [px(64)][XS_W] floats, lives before PASS A

    // ---- stage: xs / weight tables / pooled_s ----
    if (tid < 96) pooled_s[tid] = 0.f;
    for (int idx = tid; idx < 864; idx += 512) {
        int t5 = idx / 96, c = idx - t5 * 96;
        wls[idx] = dw2w[c * 9 + t5];
    }
    for (int idx = tid; idx < 216; idx += 512) {
        int g = idx / 9, tap = idx - g * 9;
        wats[idx * 2]     = c2w1[g * 18 + tap];
        wats[idx * 2 + 1] = c2w1[g * 18 + 9 + tap];
    }
    if (tid < 24) c2b1s[tid] = c2b1[tid];
    for (int idx = tid; idx < 144 * 12; idx += 512) {
        int pos = idx / 12, jp = idx - pos * 12;
        int gy = ty * 8 - 2 + pos / 12, gx = tx * 8 - 2 + pos % 12;
        uint2 v = {0u, 0u};
        if (((unsigned)gy < (unsigned)HH) & ((unsigned)gx < (unsigned)WW))
            v = *(const uint2*)&x_p[((size_t)b * HWP + gy * WW + gx) * 24 + jp * 2];
        xs[pos * XS_W + jp * 2]     = v.x;      // b32 pair: odd row stride breaks 8B align
        xs[pos * XS_W + jp * 2 + 1] = v.y;
    }
    __syncthreads();

    int p_t = wp * 16 + i16;
    int pyT = p_t >> 3, pxT = p_t & 7;
    int gp = (ty * 8 + pyT) * WW + tx * 8 + pxT;
    uint4 z4 = {0u, 0u, 0u, 0u};

    // ---- att: grouped conv t (8 threads/pixel across wave pair, 3 groups each) ----
    #pragma unroll
    for (int ci = 0; ci < 3; ++ci) {
        int g = q * 6 + wh * 3 + ci;
        float acc = c2b1s[g];
        #pragma unroll
        for (int di = 0; di < 3; ++di)
          #pragma unroll
          for (int dj = 0; dj < 3; ++dj) {
              unsigned pr = xs[((pyT + 1 + di) * 12 + pxT + 1 + dj) * XS_W + g];
              f32x2 w2 = *(const f32x2*)&wats[(g * 9 + di * 3 + dj) * 2];
              acc += w2.x * bfpair_lo(pr) + w2.y * bfpair_hi(pr);
          }
        att_tf[p_t * XS_W + g] = acc;
    }
    __syncthreads();

    // ---- att: gate + skip via permuted-A MFMA -> afrag in registers ----
    bf16x8 afrag;
    {
        int p26 = p_t * XS_W;
        unsigned tgd[4];
        #pragma unroll
        for (int i2 = 0; i2 < 4; ++i2) {
            int k0 = q * 8 + 2 * i2;
            int k1 = k0 + 1;
            float v0 = (k0 < 12) ? att_tf[p26 + k0] * att_tf[p26 + 12 + k0] : (k0 == 12 ? 1.f : 0.f);
            float v1 = (k1 < 12) ? att_tf[p26 + k1] * att_tf[p26 + 12 + k1] : (k1 == 12 ? 1.f : 0.f);
            tgd[i2] = pack2bf(v0, v1);
        }
        uint4 tgr = {tgd[0], tgd[1], tgd[2], tgd[3]};
        bf16x8 btg = __builtin_bit_cast(bf16x8, tgr);

        int cen = (pyT + 2) * 12 + (pxT + 2);
        int cb = cen * XS_W + q * 4;
        uint4 bx0r = {xs[cb], xs[cb + 1], xs[cb + 2], xs[cb + 3]};
        uint4 bx1r = z4;                // MUST be zeroed for q>=2: xs entries 24+ are
        if (q < 2) {                    // unwritten garbage; 0-weight x NaN = NaN
            int cb2 = cen * XS_W + 16 + q * 4;
            bx1r.x = xs[cb2]; bx1r.y = xs[cb2 + 1]; bx1r.z = xs[cb2 + 2]; bx1r.w = xs[cb2 + 3];
        }
        bf16x8 bx0 = __builtin_bit_cast(bf16x8, bx0r);
        bf16x8 bx1 = __builtin_bit_cast(bf16x8, bx1r);

        float attv[8];
        #pragma unroll
        for (int nt2 = 0; nt2 < 2; ++nt2) {
            bf16x8 ag  = __builtin_bit_cast(bf16x8, Ag[nt2 * 64 + lane]);
            bf16x8 as0 = __builtin_bit_cast(bf16x8, Aps[nt2 * 64 + lane]);
            bf16x8 as1 = __builtin_bit_cast(bf16x8, Aps[(2 + nt2) * 64 + lane]);
            f32x4 z = {0.f, 0.f, 0.f, 0.f};
            f32x4 c = __builtin_amdgcn_mfma_f32_16x16x32_bf16(ag, btg, z, 0, 0, 0);
            c = __builtin_amdgcn_mfma_f32_16x16x32_bf16(as1, bx1, c, 0, 0, 0);
            c = __builtin_amdgcn_mfma_f32_16x16x32_bf16(as0, bx0, c, 0, 0, 0);
            #pragma unroll
            for (int r = 0; r < 4; ++r) attv[nt2 * 4 + r] = c[r];
        }
        uint4 au = {pack2bf(attv[0], attv[1]), pack2bf(attv[2], attv[3]),
                    pack2bf(attv[4], attv[5]), pack2bf(attv[6], attv[7])};
        afrag = __builtin_bit_cast(bf16x8, au);
    }
    __syncthreads();   // att_tf dead -> hsw free for PASS A

    // ========== PASS A: h(c1) on 12x12 halo via MFMA ==========
    // Each wave: own rg (6 nt). rg8's 6 nt-tiles spread one-each over waves 1..6.
    {
        {
            int rg = wy;
            int hp = rg * 16 + i16;
            int ab = hp * XS_W + q * 4;
            uint4 a0r = {xs[ab], xs[ab + 1], xs[ab + 2], xs[ab + 3]};
            uint4 a1r = z4;
            if (q < 2) {
                int ab2 = hp * XS_W + 16 + q * 4;
                a1r.x = xs[ab2]; a1r.y = xs[ab2 + 1]; a1r.z = xs[ab2 + 2]; a1r.w = xs[ab2 + 3];
            }
            bf16x8 a0 = __builtin_bit_cast(bf16x8, a0r);
            bf16x8 a1 = __builtin_bit_cast(bf16x8, a1r);
            int rowb = rg * 16 + 4 * q;
            #pragma unroll
            for (int nt = 0; nt < 6; ++nt) {
                bf16x8 b0 = __builtin_bit_cast(bf16x8, Bpw[(size_t)((6 + nt) << 6) + lane]);
                bf16x8 b1 = __builtin_bit_cast(bf16x8, Bpw[(size_t)((18 + nt) << 6) + lane]);
                f32x4 z = {0.f, 0.f, 0.f, 0.f};
                f32x4 c = __builtin_amdgcn_mfma_f32_16x16x32_bf16(a1, b1, z, 0, 0, 0);
                c = __builtin_amdgcn_mfma_f32_16x16x32_bf16(a0, b0, c, 0, 0, 0);
                #pragma unroll
                for (int r = 0; r < 4; ++r)
                    st_bf_hi(&hsw[(rowb + r) * HS_W + nt * 16 + i16], c[r]);
            }
        }
        if (wy >= 1 && wy <= 6) {                 // rg8, one nt-tile per wave
            int hp = 128 + i16;
            int ab = hp * XS_W + q * 4;
            uint4 a0r = {xs[ab], xs[ab + 1], xs[ab + 2], xs[ab + 3]};
            uint4 a1r = z4;
            if (q < 2) {
                int ab2 = hp * XS_W + 16 + q * 4;
                a1r.x = xs[ab2]; a1r.y = xs[ab2 + 1]; a1r.z = xs[ab2 + 2]; a1r.w = xs[ab2 + 3];
            }
            bf16x8 a0 = __builtin_bit_cast(bf16x8, a0r);
            bf16x8 a1 = __builtin_bit_cast(bf16x8, a1r);
            int rowb = 128 + 4 * q;
            int nt = wy - 1;
            bf16x8 b0 = __builtin_bit_cast(bf16x8, Bpw[(size_t)((6 + nt) << 6) + lane]);
            bf16x8 b1 = __builtin_bit_cast(bf16x8, Bpw[(size_t)((18 + nt) << 6) + lane]);
            f32x4 z = {0.f, 0.f, 0.f, 0.f};
            f32x4 c = __builtin_amdgcn_mfma_f32_16x16x32_bf16(a1, b1, z, 0, 0, 0);
            c = __builtin_amdgcn_mfma_f32_16x16x32_bf16(a0, b0, c, 0, 0, 0);
            #pragma unroll
            for (int r = 0; r < 4; ++r)
                st_bf_hi(&hsw[(rowb + r) * HS_W + nt * 16 + i16], c[r]);
        }
    }
    __syncthreads();

    // ---- depthwise c1 -> uf on 10x10 halo (us2p): 24 (cq,half) sub-units over 8 waves ----
    #pragma unroll 1
    for (int it = 0; it < 3; ++it) {
        int su = wy * 3 + it;                  // 0..23
        int cq = su >> 1;                      // wave-uniform -> s_loads for weights
        const float* w9 = c1w2 + cq * 8 * 9;
        int hp2 = (su & 1) * 50 + lane;
        if (lane < 50) {
            int py2 = hp2 / 10, px2 = hp2 - py2 * 10;
            float acc[8];
            #pragma unroll
            for (int c = 0; c < 8; ++c) acc[c] = 0.f;
            #pragma unroll
            for (int di = 0; di < 3; ++di)
              #pragma unroll
              for (int dj = 0; dj < 3; ++dj) {
                  int rb = ((py2 + di) * 12 + px2 + dj) * HS_W + cq * 8;
                  unsigned pp[4];
                  pp[0] = *(const unsigned*)&hsw[rb];
                  pp[1] = *(const unsigned*)&hsw[rb + 2];
                  pp[2] = *(const unsigned*)&hsw[rb + 4];
                  pp[3] = *(const unsigned*)&hsw[rb + 6];
                  #pragma unroll
                  for (int c2 = 0; c2 < 4; ++c2) {
                      acc[2*c2]   += w9[(2*c2) * 9 + di * 3 + dj]   * bfpair_lo(pp[c2]);
                      acc[2*c2+1] += w9[(2*c2+1) * 9 + di * 3 + dj] * bfpair_hi(pp[c2]);
                  }
              }
            int wb = hp2 * US_W + cq * 8;
            *(unsigned*)&us2p[wb]     = pack2bf(acc[0], acc[1]);
            *(unsigned*)&us2p[wb + 2] = pack2bf(acc[2], acc[3]);
            *(unsigned*)&us2p[wb + 4] = pack2bf(acc[4], acc[5]);
            *(unsigned*)&us2p[wb + 6] = pack2bf(acc[6], acc[7]);
        }
    }
    __syncthreads();

    // ========== PASS B: h(dw) on 10x10 halo via MFMA (7 row-groups, 1 per wave) ==========
    if (wy < 7) {
        int rg = wy;
        int hp = rg * 16 + i16;
        bool okp = hp < 100;
        int hy = hp / 10, hx = hp - hy * 10;
        int pos = okp ? ((hy + 1) * 12 + hx + 1) : 0;
        int ab = pos * XS_W + q * 4;
        uint4 a0r = {xs[ab], xs[ab + 1], xs[ab + 2], xs[ab + 3]};
        uint4 a1r = z4;
        if (q < 2) {
            int ab2 = pos * XS_W + 16 + q * 4;
            a1r.x = xs[ab2]; a1r.y = xs[ab2 + 1]; a1r.z = xs[ab2 + 2]; a1r.w = xs[ab2 + 3];
        }
        bf16x8 a0 = __builtin_bit_cast(bf16x8, a0r);
        bf16x8 a1 = __builtin_bit_cast(bf16x8, a1r);
        int rowb = rg * 16 + 4 * q;
        #pragma unroll
        for (int nt = 0; nt < 6; ++nt) {
            bf16x8 b0 = __builtin_bit_cast(bf16x8, Bpw[(size_t)(nt << 6) + lane]);
            bf16x8 b1 = __builtin_bit_cast(bf16x8, Bpw[(size_t)((12 + nt) << 6) + lane]);
            f32x4 z = {0.f, 0.f, 0.f, 0.f};
            f32x4 c = __builtin_amdgcn_mfma_f32_16x16x32_bf16(a1, b1, z, 0, 0, 0);
            c = __builtin_amdgcn_mfma_f32_16x16x32_bf16(a0, b0, c, 0, 0, 0);
            #pragma unroll
            for (int r = 0; r < 4; ++r)
                st_bf_hi(&hsw[(rowb + r) * HS_W + nt * 16 + i16], c[r]);  // rows>=100 harmless
        }
    }
    __syncthreads();

    // ---- depthwise dw -> gelu(x1) for OWN pixel, 12 channels (this wave's half) ----
    f32x2 greg[6];
    {
        int base = q * 24 + wh * 12;
        #pragma unroll
        for (int cc = 0; cc < 6; ++cc) {
            int c0 = base + 2 * cc;
            f32x2 acc = {0.f, 0.f};
            #pragma unroll
            for (int di = 0; di < 3; ++di)
              #pragma unroll
              for (int dj = 0; dj < 3; ++dj) {
                  unsigned pr = *(const unsigned*)&hsw[((pyT + di) * 10 + pxT + dj) * HS_W + c0];
                  f32x2 hv = {bfpair_lo(pr), bfpair_hi(pr)};
                  f32x2 wv = *(const f32x2*)&wls[(di * 3 + dj) * 96 + c0];
                  acc += wv * hv;
              }
            greg[cc].x = gelu(acc.x);
            greg[cc].y = gelu(acc.y);
        }
    }
    // no barrier needed: KBA never writes hsw

    // ========== KBA: permuted-A MFMA, 6 chunks per wave, BpkA double-buffered in VGPRs ==========
    unsigned* cmb = comb_bf + ((size_t)b * HWP + gp) * 48 + q * 12;
    int hpC = (pyT + 1) * 10 + pxT + 1;
    const uint4* bpk_base = BpkA + (size_t)(wh * 60) * 64 + lane;   // this half's chunk stream

    uint4 buf[2][10];
    #pragma unroll
    for (int nt = 0; nt < 10; ++nt) buf[0][nt] = bpk_base[(size_t)nt << 6];

    #pragma unroll
    for (int cl = 0; cl < 6; ++cl) {              // fully unrolled: buf indices static
        int chunk = wh * 6 + cl;
        // prefetch next chunk's 10 A-operands while this chunk computes
        if (cl < 5) {
            #pragma unroll
            for (int nt = 0; nt < 10; ++nt)
                buf[(cl + 1) & 1][nt] = bpk_base[(size_t)(((cl + 1) * 10 + nt)) << 6];
        }
        int c0 = q * 24 + 2 * chunk;
        // issue LDS reads early so they overlap the MFMA cluster
        float u[18];
        #pragma unroll
        for (int i = 0; i < 3; ++i)
          #pragma unroll
          for (int j = 0; j < 3; ++j) {
              unsigned pr = *(const unsigned*)&us2p[((pyT + i) * 10 + pxT + j) * US_W + c0];
              u[i * 3 + j]     = bfpair_lo(pr);
              u[9 + i * 3 + j] = bfpair_hi(pr);
          }
        unsigned sp = *(const unsigned*)&us2p[hpC * US_W + c0];
        f32x4 cf[10];
        #pragma unroll
        for (int nt = 0; nt < 10; ++nt) {
            bf16x8 aW = __builtin_bit_cast(bf16x8, buf[cl & 1][nt]);
            f32x4 z = {0.f, 0.f, 0.f, 0.f};
            cf[nt] = __builtin_amdgcn_mfma_f32_16x16x32_bf16(aW, afrag, z, 0, 0, 0);
        }
        float acc0 = cf[4][2];           // bias slots
        float acc1 = cf[9][2];
        #pragma unroll
        for (int m = 0; m < 16; ++m) {
            acc0 += cf[m >> 2][m & 3]       * u[m];
            acc1 += cf[5 + (m >> 2)][m & 3] * u[m];
        }
        acc0 += cf[4][0] * u[16] + cf[4][1] * u[17];
        acc1 += cf[9][0] * u[16] + cf[9][1] * u[17];

        float x20 = acc0 + bfpair_lo(sp);     // ga1 pre-folded into BpkA
        float x21 = acc1 + bfpair_hi(sp);
        float cv0 = greg[cl].x * x20;
        float cv1 = greg[cl].y * x21;
        cmb[chunk] = pack2bf(cv0, cv1);
        float r0 = cv0, r1 = cv1;
        #pragma unroll
        for (int s = 1; s < 16; s <<= 1) {
            r0 += __shfl_xor(r0, s, 64);
            r1 += __shfl_xor(r1, s, 64);
        }
        if (i16 == 0) {
            atomicAdd(&pooled_s[c0], r0);
            atomicAdd(&pooled_s[c0 + 1], r1);
        }
    }
    __syncthreads();
    if (tid < 96) atomicAdd(&pooled[b * HIDC + tid], pooled_s[tid]);
}

// ---------------- K2: sv (fused) + out = proj1x1( comb * sv ) ----------------
__global__ __launch_bounds__(256) void k_final(
    const unsigned* __restrict__ comb_bf, const float* __restrict__ pooled,
    const float* __restrict__ scaw, const float* __restrict__ scab,
    const float* __restrict__ projw, float* __restrict__ out)
{
    __shared__ float svs[96];
    __shared__ float cs[96][66];
    int tid = threadIdx.x;
    int blk = blockIdx.x;
    int p0 = blk * 64;
    int b = p0 >> 14;
    if (tid < 96) {
        float dot = 0.f;
        const float* pr = pooled + b * 96;
        const float* wr = scaw + tid * 96;
        #pragma unroll 4
        for (int k = 0; k < 96; ++k) dot += wr[k] * pr[k];
        svs[tid] = scab[tid] + dot * (1.0f / (float)HWP);
    }
    __syncthreads();
    for (int idx = tid; idx < 64 * 12; idx += 256) {
        int px = idx / 12, cq = idx - px * 12;
        uint4 v = *(const uint4*)&comb_bf[(size_t)(p0 + px) * 48 + cq * 4];
        int k0 = cq * 8;
        unsigned pp[4] = {v.x, v.y, v.z, v.w};
        #pragma unroll
        for (int j = 0; j < 4; ++j) {
            cs[k0 + 2*j][px]     = bfpair_lo(pp[j]) * svs[k0 + 2*j];
            cs[k0 + 2*j + 1][px] = bfpair_hi(pp[j]) * svs[k0 + 2*j + 1];
        }
    }
    __syncthreads();
    int l = tid & 63, w = tid >> 6;
    int o0 = w * 12;
    float acc[12];
    #pragma unroll
    for (int o = 0; o < 12; ++o) acc[o] = 0.f;
    #pragma unroll 4
    for (int k = 0; k < 96; ++k) {
        float v = cs[k][l];
        #pragma unroll
        for (int o = 0; o < 12; ++o)
            acc[o] += projw[(o0 + o) * 96 + k] * v;      // wave-uniform -> s_loads
    }
    float* ob = out + (size_t)b * DIMC * HWP + (p0 & 16383) + l;
    #pragma unroll
    for (int o = 0; o < 12; ++o)
        ob[(o0 + o) * HWP] = acc[o];
}

extern "C" void kernel_launch(void* const* d_in, const int* in_sizes, int n_in,
                              void* d_out, int out_size, void* d_ws, size_t ws_size,
                              hipStream_t stream)
{
    const float* x     = (const float*)d_in[0];
    const float* dw1w  = (const float*)d_in[1];
    const float* dw2w  = (const float*)d_in[2];
    const float* projw = (const float*)d_in[3];
    const float* scaw  = (const float*)d_in[4];
    const float* scab  = (const float*)d_in[5];
    const float* c1w1  = (const float*)d_in[6];
    const float* c1w2  = (const float*)d_in[7];
    const float* kbaw  = (const float*)d_in[8];
    const float* kbab  = (const float*)d_in[9];
    const float* c2w1  = (const float*)d_in[10];
    const float* c2b1  = (const float*)d_in[11];
    const float* c2w2  = (const float*)d_in[12];
    const float* c2b2  = (const float*)d_in[13];
    const float* c211w = (const float*)d_in[14];
    const float* c211b = (const float*)d_in[15];
    const float* attg  = (const float*)d_in[16];
    const float* ga1   = (const float*)d_in[17];

    unsigned* x_p     = (unsigned*)d_ws;                           // 1,572,864 dw
    unsigned* comb_bf = x_p + (size_t)BB * HWP * 24;               // 3,145,728 dw
    float* pooled     = (float*)(comb_bf + (size_t)BB * HWP * 48); // 384 f
    unsigned short* BpkA = (unsigned short*)(pooled + BB * HIDC);  // 61,440 ush
    unsigned short* Bpw  = BpkA + 61440;                           // 12,288 ush
    unsigned short* Aps  = Bpw + 12288;                            //  2,048 ush
    unsigned short* Ag   = Aps + 2048;                             //  1,024 ush

    k_prep <<<556,  256, 0, stream>>>(x, kbaw, kbab, dw1w, c1w1, ga1, c211w, c2w2, c2b2,
                                      c211b, attg, BpkA, Bpw, Aps, Ag, x_p, pooled);
    k_mff  <<<1024, dim3(64,8,1), 0, stream>>>(x_p, (const uint4*)BpkA, (const uint4*)Bpw,
                                               (const uint4*)Aps, (const uint4*)Ag,
                                               c1w2, dw2w, c2w1, c2b1, comb_bf, pooled);
    k_final<<<1024, 256, 0, stream>>>(comb_bf, pooled, scaw, scab, projw, (float*)d_out);
}

// Round 4
// 203.968 us; speedup vs baseline: 1.0439x; 1.0439x over previous
//
#include <hip/hip_runtime.h>
#include <math.h>

#define BB 4
#define HH 128
#define WW 128
#define HWP (HH*WW)
#define DIMC 48
#define HIDC 96
#define NSETC 32

// Odd-dword LDS row strides (bank-conflict fix):
#define XS_W 27     // xs row stride in dwords
#define HS_W 102    // hsw row stride in ushorts = 51 dwords
#define US_W 102    // us2p row stride in ushorts = 51 dwords

typedef __attribute__((ext_vector_type(8))) short bf16x8;
typedef __attribute__((ext_vector_type(4))) float f32x4;
typedef __attribute__((ext_vector_type(2))) float f32x2;

static __device__ __forceinline__ unsigned short f2bf(float f) {   // RNE (pack path, cold)
    union { float f; unsigned u; } v; v.f = f;
    unsigned r = (v.u + 0x7FFFu + ((v.u >> 16) & 1u)) >> 16;
    return (unsigned short)r;
}
static __device__ __forceinline__ unsigned rnd_bf(float f) {       // +0x8000 round-half-up
    union { float f; unsigned u; } v; v.f = f;
    return v.u + 0x8000u;
}
static __device__ __forceinline__ unsigned pack2bf(float lo, float hi) {
    return __builtin_amdgcn_perm(rnd_bf(hi), rnd_bf(lo), 0x07060302u);
}
static __device__ __forceinline__ void st_bf_hi(unsigned short* p, float f) {
    *p = (unsigned short)(rnd_bf(f) >> 16);
}
static __device__ __forceinline__ float bfpair_lo(unsigned pr) {
    union { unsigned u; float f; } v; v.u = pr << 16; return v.f;
}
static __device__ __forceinline__ float bfpair_hi(unsigned pr) {
    union { unsigned u; float f; } v; v.u = pr & 0xffff0000u; return v.f;
}
static __device__ __forceinline__ float gelu(float x) {
    return 0.5f * x * (1.0f + erff(x * 0.70710678118654752f));
}
// Async global->LDS DMA, 16 B/lane. LDS dest is WAVE-UNIFORM base (+lane*16 by HW);
// global src is per-lane. Zero VGPR cost -- the whole point vs round-3's spill.
static __device__ __forceinline__ void gll16(const void* g, void* l) {
    __builtin_amdgcn_global_load_lds(
        (const __attribute__((address_space(1))) void*)g,
        (__attribute__((address_space(3))) void*)l, 16, 0, 0);
}

// ---------------- K0: weight pack (permuted A-operand layouts) + x transpose ----------------
__global__ __launch_bounds__(256) void k_prep(
    const float* __restrict__ x,
    const float* __restrict__ kbaw, const float* __restrict__ kbab,
    const float* __restrict__ dw1w, const float* __restrict__ c1w1,
    const float* __restrict__ ga1,  const float* __restrict__ c211w,
    const float* __restrict__ c2w2, const float* __restrict__ c2b2,
    const float* __restrict__ c211b, const float* __restrict__ attg,
    unsigned short* __restrict__ Bpk, unsigned short* __restrict__ Bpw,
    unsigned short* __restrict__ Aps, unsigned short* __restrict__ Ag,
    unsigned* __restrict__ x_p, float* __restrict__ pooled)
{
    __shared__ unsigned ts[256 * 26];
    int blk = blockIdx.x, tid = threadIdx.x;
    if (blk < 300) {
        int t = blk * 256 + tid;
        if (t < 61440) {                         // BpkA
            int j = t & 7, lane = (t >> 3) & 63, tile = t >> 9;
            int chunk = tile / 10, nt = tile - chunk * 10;
            int m = lane & 15, qn = lane >> 4;
            int lc = 4 * nt + (m & 3);           // local col within this q's 40-block
            int o = lc / 20, tt = lc % 20;
            int c = (m >> 2) * 24 + 2 * chunk + o;
            int n = qn * 8 + j;
            float v = 0.f;
            if (tt < 18)       v = kbaw[n * 1728 + (c >> 1) * 36 + (c & 1) * 18 + tt] * ga1[c];
            else if (tt == 18) v = kbab[n * 96 + c] * ga1[c];
            Bpk[t] = f2bf(v);
        } else if (t < 73728) {                  // Bpw (B operand)
            int u = t - 61440;
            int s = u / 6144;
            int rem = u % 6144;
            int nt = rem >> 9;
            int lane = (rem >> 3) & 63, j = rem & 7;
            int k = s * 32 + ((lane >> 4) << 3) + j;
            int col = (nt << 4) + (lane & 15);
            float v = 0.f;
            if (k < 48) v = (col < 96) ? dw1w[col * 48 + k] : c1w1[(col - 96) * 48 + k];
            Bpw[u] = f2bf(v);
        } else if (t < 75776) {                  // Aps (skip 1x1 A-operand)
            int u = t - 73728;
            int j = u & 7, lane = (u >> 3) & 63, tile = u >> 9;   // 0..3 = kt*2+nt2
            int kt = tile >> 1, nt2 = tile & 1;
            int m = lane & 15, qn = lane >> 4;
            int n = 8 * (m >> 2) + 4 * nt2 + (m & 3);
            int k = kt * 32 + qn * 8 + j;
            Aps[u] = f2bf(k < 48 ? c211w[n * 48 + k] : 0.f);
        } else if (t < 76800) {                  // Ag (gate 1x1 A-operand, biases at k=12)
            int u = t - 75776;
            int j = u & 7, lane = (u >> 3) & 63, nt2 = u >> 9;    // 0..1
            int m = lane & 15, qn = lane >> 4;
            int n = 8 * (m >> 2) + 4 * nt2 + (m & 3);
            int k = qn * 8 + j;
            float v = 0.f;
            if (k < 12)       v = c2w2[n * 12 + k] * attg[n];
            else if (k == 12) v = c2b2[n] * attg[n] + c211b[n];
            Ag[u] = f2bf(v);
        }
    } else {
        int xblk = blk - 300;
        if (xblk == 0) {
            for (int i = tid; i < BB * HIDC; i += 256) pooled[i] = 0.f;
        }
        int b = xblk >> 6;
        int p0 = (xblk & 63) << 8;
        const float* xb = x + (size_t)b * DIMC * HWP + p0;
        #pragma unroll
        for (int c2 = 0; c2 < 24; ++c2) {
            float lo = xb[(2 * c2) * HWP + tid];
            float hi = xb[(2 * c2 + 1) * HWP + tid];
            ts[tid * 26 + c2] = pack2bf(lo, hi);
        }
        __syncthreads();
        unsigned* dst = x_p + ((size_t)b * HWP + p0) * 24;
        for (int idx = tid; idx < 256 * 24; idx += 256) {
            int px = idx / 24, j2 = idx - px * 24;
            dst[px * 24 + j2] = ts[px * 26 + j2];
        }
    }
}

// ---------------- K1 (mega-fused): att + 1x1 MFMA + depthwise + KBA -> comb(bf16) ----------------
// 1024 blocks, dim3(64,8); 2 blocks/CU (LDS ~69.3 KB) -> 4 waves/SIMD.
// Round-4: KBA's BpkA stream staged through LDS via global_load_lds DMA (zero VGPR),
// double-buffered over the xs+hsw pool (both dead after greg). Replaces 60 per-wave L2
// loads with 10 conflict-free ds_read_b128 per chunk; kills round-3's scratch spill.
__global__ __launch_bounds__(512, 2) void k_mff(
    const unsigned* __restrict__ x_p,
    const uint4* __restrict__ BpkA, const uint4* __restrict__ Bpw,
    const uint4* __restrict__ Aps,  const uint4* __restrict__ Ag,
    const float* __restrict__ c1w2, const float* __restrict__ dw2w,
    const float* __restrict__ c2w1, const float* __restrict__ c2b1,
    unsigned* __restrict__ comb_bf, float* __restrict__ pooled)
{
    // xs | hsw share one pool so the KBA staging (2 x 20480 B) can overlay both.
    __shared__ __attribute__((aligned(16))) unsigned smem_pool[144 * XS_W + (144 * HS_W) / 2]; // 44.9 KB
    __shared__ unsigned short us2p[100 * US_W];                             // uf halo (19.9 KB)
    __shared__ float wls[864 + 432 + 24];                                   // dw2w | c2w1 | c2b1 (5.3 KB)
    __shared__ float pooled_s[96];

    unsigned* xs = smem_pool;                                   // [144][XS_W] bf16-pairs
    unsigned short* hsw = (unsigned short*)(smem_pool + 144 * XS_W); // [144][HS_W]

    int lane = threadIdx.x, wy = threadIdx.y;   // wy 0..7
    int tid = wy * 64 + lane;
    int blk = blockIdx.x;
    int b = blk >> 8, ty = (blk >> 4) & 15, tx = blk & 15;
    int q = lane >> 4, i16 = lane & 15;
    int wh = wy >> 2;          // channel/chunk half (0/1)
    int wp = wy & 3;           // pixel group 0..3

    float* wats  = wls + 864;    // [g][tap][2]
    float* c2b1s = wls + 864 + 432;
    float* att_tf = (float*)hsw; // [px(64)][XS_W] floats, lives before PASS A

    // ---- stage: xs / weight tables / pooled_s ----
    if (tid < 96) pooled_s[tid] = 0.f;
    for (int idx = tid; idx < 864; idx += 512) {
        int t5 = idx / 96, c = idx - t5 * 96;
        wls[idx] = dw2w[c * 9 + t5];
    }
    for (int idx = tid; idx < 216; idx += 512) {
        int g = idx / 9, tap = idx - g * 9;
        wats[idx * 2]     = c2w1[g * 18 + tap];
        wats[idx * 2 + 1] = c2w1[g * 18 + 9 + tap];
    }
    if (tid < 24) c2b1s[tid] = c2b1[tid];
    for (int idx = tid; idx < 144 * 12; idx += 512) {
        int pos = idx / 12, jp = idx - pos * 12;
        int gy = ty * 8 - 2 + pos / 12, gx = tx * 8 - 2 + pos % 12;
        uint2 v = {0u, 0u};
        if (((unsigned)gy < (unsigned)HH) & ((unsigned)gx < (unsigned)WW))
            v = *(const uint2*)&x_p[((size_t)b * HWP + gy * WW + gx) * 24 + jp * 2];
        xs[pos * XS_W + jp * 2]     = v.x;
        xs[pos * XS_W + jp * 2 + 1] = v.y;
    }
    __syncthreads();

    int p_t = wp * 16 + i16;
    int pyT = p_t >> 3, pxT = p_t & 7;
    int gp = (ty * 8 + pyT) * WW + tx * 8 + pxT;
    uint4 z4 = {0u, 0u, 0u, 0u};

    // ---- att: grouped conv t (8 threads/pixel across wave pair, 3 groups each) ----
    #pragma unroll
    for (int ci = 0; ci < 3; ++ci) {
        int g = q * 6 + wh * 3 + ci;
        float acc = c2b1s[g];
        #pragma unroll
        for (int di = 0; di < 3; ++di)
          #pragma unroll
          for (int dj = 0; dj < 3; ++dj) {
              unsigned pr = xs[((pyT + 1 + di) * 12 + pxT + 1 + dj) * XS_W + g];
              f32x2 w2 = *(const f32x2*)&wats[(g * 9 + di * 3 + dj) * 2];
              acc += w2.x * bfpair_lo(pr) + w2.y * bfpair_hi(pr);
          }
        att_tf[p_t * XS_W + g] = acc;
    }
    __syncthreads();

    // ---- att: gate + skip via permuted-A MFMA -> afrag in registers ----
    bf16x8 afrag;
    {
        int p26 = p_t * XS_W;
        unsigned tgd[4];
        #pragma unroll
        for (int i2 = 0; i2 < 4; ++i2) {
            int k0 = q * 8 + 2 * i2;
            int k1 = k0 + 1;
            float v0 = (k0 < 12) ? att_tf[p26 + k0] * att_tf[p26 + 12 + k0] : (k0 == 12 ? 1.f : 0.f);
            float v1 = (k1 < 12) ? att_tf[p26 + k1] * att_tf[p26 + 12 + k1] : (k1 == 12 ? 1.f : 0.f);
            tgd[i2] = pack2bf(v0, v1);
        }
        uint4 tgr = {tgd[0], tgd[1], tgd[2], tgd[3]};
        bf16x8 btg = __builtin_bit_cast(bf16x8, tgr);

        int cen = (pyT + 2) * 12 + (pxT + 2);
        int cb = cen * XS_W + q * 4;
        uint4 bx0r = {xs[cb], xs[cb + 1], xs[cb + 2], xs[cb + 3]};
        uint4 bx1r = z4;                // MUST be zeroed for q>=2: xs entries 24+ are
        if (q < 2) {                    // unwritten garbage; 0-weight x NaN = NaN
            int cb2 = cen * XS_W + 16 + q * 4;
            bx1r.x = xs[cb2]; bx1r.y = xs[cb2 + 1]; bx1r.z = xs[cb2 + 2]; bx1r.w = xs[cb2 + 3];
        }
        bf16x8 bx0 = __builtin_bit_cast(bf16x8, bx0r);
        bf16x8 bx1 = __builtin_bit_cast(bf16x8, bx1r);

        float attv[8];
        #pragma unroll
        for (int nt2 = 0; nt2 < 2; ++nt2) {
            bf16x8 ag  = __builtin_bit_cast(bf16x8, Ag[nt2 * 64 + lane]);
            bf16x8 as0 = __builtin_bit_cast(bf16x8, Aps[nt2 * 64 + lane]);
            bf16x8 as1 = __builtin_bit_cast(bf16x8, Aps[(2 + nt2) * 64 + lane]);
            f32x4 z = {0.f, 0.f, 0.f, 0.f};
            f32x4 c = __builtin_amdgcn_mfma_f32_16x16x32_bf16(ag, btg, z, 0, 0, 0);
            c = __builtin_amdgcn_mfma_f32_16x16x32_bf16(as1, bx1, c, 0, 0, 0);
            c = __builtin_amdgcn_mfma_f32_16x16x32_bf16(as0, bx0, c, 0, 0, 0);
            #pragma unroll
            for (int r = 0; r < 4; ++r) attv[nt2 * 4 + r] = c[r];
        }
        uint4 au = {pack2bf(attv[0], attv[1]), pack2bf(attv[2], attv[3]),
                    pack2bf(attv[4], attv[5]), pack2bf(attv[6], attv[7])};
        afrag = __builtin_bit_cast(bf16x8, au);
    }
    __syncthreads();   // att_tf dead -> hsw free for PASS A

    // ========== PASS A: h(c1) on 12x12 halo via MFMA ==========
    // Each wave: own rg (6 nt). rg8's 6 nt-tiles spread one-each over waves 1..6.
    {
        {
            int rg = wy;
            int hp = rg * 16 + i16;
            int ab = hp * XS_W + q * 4;
            uint4 a0r = {xs[ab], xs[ab + 1], xs[ab + 2], xs[ab + 3]};
            uint4 a1r = z4;
            if (q < 2) {
                int ab2 = hp * XS_W + 16 + q * 4;
                a1r.x = xs[ab2]; a1r.y = xs[ab2 + 1]; a1r.z = xs[ab2 + 2]; a1r.w = xs[ab2 + 3];
            }
            bf16x8 a0 = __builtin_bit_cast(bf16x8, a0r);
            bf16x8 a1 = __builtin_bit_cast(bf16x8, a1r);
            int rowb = rg * 16 + 4 * q;
            #pragma unroll
            for (int nt = 0; nt < 6; ++nt) {
                bf16x8 b0 = __builtin_bit_cast(bf16x8, Bpw[(size_t)((6 + nt) << 6) + lane]);
                bf16x8 b1 = __builtin_bit_cast(bf16x8, Bpw[(size_t)((18 + nt) << 6) + lane]);
                f32x4 z = {0.f, 0.f, 0.f, 0.f};
                f32x4 c = __builtin_amdgcn_mfma_f32_16x16x32_bf16(a1, b1, z, 0, 0, 0);
                c = __builtin_amdgcn_mfma_f32_16x16x32_bf16(a0, b0, c, 0, 0, 0);
                #pragma unroll
                for (int r = 0; r < 4; ++r)
                    st_bf_hi(&hsw[(rowb + r) * HS_W + nt * 16 + i16], c[r]);
            }
        }
        if (wy >= 1 && wy <= 6) {                 // rg8, one nt-tile per wave
            int hp = 128 + i16;
            int ab = hp * XS_W + q * 4;
            uint4 a0r = {xs[ab], xs[ab + 1], xs[ab + 2], xs[ab + 3]};
            uint4 a1r = z4;
            if (q < 2) {
                int ab2 = hp * XS_W + 16 + q * 4;
                a1r.x = xs[ab2]; a1r.y = xs[ab2 + 1]; a1r.z = xs[ab2 + 2]; a1r.w = xs[ab2 + 3];
            }
            bf16x8 a0 = __builtin_bit_cast(bf16x8, a0r);
            bf16x8 a1 = __builtin_bit_cast(bf16x8, a1r);
            int rowb = 128 + 4 * q;
            int nt = wy - 1;
            bf16x8 b0 = __builtin_bit_cast(bf16x8, Bpw[(size_t)((6 + nt) << 6) + lane]);
            bf16x8 b1 = __builtin_bit_cast(bf16x8, Bpw[(size_t)((18 + nt) << 6) + lane]);
            f32x4 z = {0.f, 0.f, 0.f, 0.f};
            f32x4 c = __builtin_amdgcn_mfma_f32_16x16x32_bf16(a1, b1, z, 0, 0, 0);
            c = __builtin_amdgcn_mfma_f32_16x16x32_bf16(a0, b0, c, 0, 0, 0);
            #pragma unroll
            for (int r = 0; r < 4; ++r)
                st_bf_hi(&hsw[(rowb + r) * HS_W + nt * 16 + i16], c[r]);
        }
    }
    __syncthreads();

    // ---- depthwise c1 -> uf on 10x10 halo (us2p): 24 (cq,half) sub-units over 8 waves ----
    #pragma unroll 1
    for (int it = 0; it < 3; ++it) {
        int su = wy * 3 + it;                  // 0..23
        int cq = su >> 1;                      // wave-uniform -> s_loads for weights
        const float* w9 = c1w2 + cq * 8 * 9;
        int hp2 = (su & 1) * 50 + lane;
        if (lane < 50) {
            int py2 = hp2 / 10, px2 = hp2 - py2 * 10;
            float acc[8];
            #pragma unroll
            for (int c = 0; c < 8; ++c) acc[c] = 0.f;
            #pragma unroll
            for (int di = 0; di < 3; ++di)
              #pragma unroll
              for (int dj = 0; dj < 3; ++dj) {
                  int rb = ((py2 + di) * 12 + px2 + dj) * HS_W + cq * 8;
                  unsigned pp[4];
                  pp[0] = *(const unsigned*)&hsw[rb];
                  pp[1] = *(const unsigned*)&hsw[rb + 2];
                  pp[2] = *(const unsigned*)&hsw[rb + 4];
                  pp[3] = *(const unsigned*)&hsw[rb + 6];
                  #pragma unroll
                  for (int c2 = 0; c2 < 4; ++c2) {
                      acc[2*c2]   += w9[(2*c2) * 9 + di * 3 + dj]   * bfpair_lo(pp[c2]);
                      acc[2*c2+1] += w9[(2*c2+1) * 9 + di * 3 + dj] * bfpair_hi(pp[c2]);
                  }
              }
            int wb = hp2 * US_W + cq * 8;
            *(unsigned*)&us2p[wb]     = pack2bf(acc[0], acc[1]);
            *(unsigned*)&us2p[wb + 2] = pack2bf(acc[2], acc[3]);
            *(unsigned*)&us2p[wb + 4] = pack2bf(acc[4], acc[5]);
            *(unsigned*)&us2p[wb + 6] = pack2bf(acc[6], acc[7]);
        }
    }
    __syncthreads();

    // ========== PASS B: h(dw) on 10x10 halo via MFMA (7 row-groups, 1 per wave) ==========
    if (wy < 7) {
        int rg = wy;
        int hp = rg * 16 + i16;
        bool okp = hp < 100;
        int hy = hp / 10, hx = hp - hy * 10;
        int pos = okp ? ((hy + 1) * 12 + hx + 1) : 0;
        int ab = pos * XS_W + q * 4;
        uint4 a0r = {xs[ab], xs[ab + 1], xs[ab + 2], xs[ab + 3]};
        uint4 a1r = z4;
        if (q < 2) {
            int ab2 = pos * XS_W + 16 + q * 4;
            a1r.x = xs[ab2]; a1r.y = xs[ab2 + 1]; a1r.z = xs[ab2 + 2]; a1r.w = xs[ab2 + 3];
        }
        bf16x8 a0 = __builtin_bit_cast(bf16x8, a0r);
        bf16x8 a1 = __builtin_bit_cast(bf16x8, a1r);
        int rowb = rg * 16 + 4 * q;
        #pragma unroll
        for (int nt = 0; nt < 6; ++nt) {
            bf16x8 b0 = __builtin_bit_cast(bf16x8, Bpw[(size_t)(nt << 6) + lane]);
            bf16x8 b1 = __builtin_bit_cast(bf16x8, Bpw[(size_t)((12 + nt) << 6) + lane]);
            f32x4 z = {0.f, 0.f, 0.f, 0.f};
            f32x4 c = __builtin_amdgcn_mfma_f32_16x16x32_bf16(a1, b1, z, 0, 0, 0);
            c = __builtin_amdgcn_mfma_f32_16x16x32_bf16(a0, b0, c, 0, 0, 0);
            #pragma unroll
            for (int r = 0; r < 4; ++r)
                st_bf_hi(&hsw[(rowb + r) * HS_W + nt * 16 + i16], c[r]);  // rows>=100 harmless
        }
    }
    __syncthreads();

    // ---- depthwise dw -> gelu(x1) for OWN pixel, 12 channels (this wave's half) ----
    f32x2 greg[6];
    {
        int base = q * 24 + wh * 12;
        #pragma unroll
        for (int cc = 0; cc < 6; ++cc) {
            int c0 = base + 2 * cc;
            f32x2 acc = {0.f, 0.f};
            #pragma unroll
            for (int di = 0; di < 3; ++di)
              #pragma unroll
              for (int dj = 0; dj < 3; ++dj) {
                  unsigned pr = *(const unsigned*)&hsw[((pyT + di) * 10 + pxT + dj) * HS_W + c0];
                  f32x2 hv = {bfpair_lo(pr), bfpair_hi(pr)};
                  f32x2 wv = *(const f32x2*)&wls[(di * 3 + dj) * 96 + c0];
                  acc += wv * hv;
              }
            greg[cc].x = gelu(acc.x);
            greg[cc].y = gelu(acc.y);
        }
    }

    // ========== KBA: BpkA staged via global_load_lds DMA, double-buffered in dead xs+hsw ==========
    // Staging layout: buf{p} at kst + p*20480; within buf: half h chunk at h*10240,
    // tile nt at nt*1024 + lane*16  (linear == BpkA's own layout; DMA writes lane-contiguous).
    __syncthreads();            // all waves done with hsw (greg) and xs -> pool reusable

    char* kst = (char*)smem_pool;
    const char* bsrc = (const char*)BpkA;
    {   // prologue: stage step 0 into buf 0
        #pragma unroll
        for (int s = wy; s < 20; s += 8) {
            int half = (s >= 10) ? 1 : 0;
            int tile = s - half * 10;
            gll16(bsrc + ((half * 6) * 10 + tile) * 1024 + lane * 16, kst + s * 1024);
        }
    }

    unsigned* cmb = comb_bf + ((size_t)b * HWP + gp) * 48 + q * 12;
    int hpC = (pyT + 1) * 10 + pxT + 1;

    #pragma unroll
    for (int cl = 0; cl < 6; ++cl) {          // fully unrolled: greg[cl]/buf parity static
        __syncthreads();                       // step cl staged & visible; buf (cl&1)^1 free
        if (cl < 5) {                          // stage step cl+1 into the other buffer
            #pragma unroll
            for (int s = wy; s < 20; s += 8) {
                int half = (s >= 10) ? 1 : 0;
                int tile = s - half * 10;
                gll16(bsrc + ((half * 6 + cl + 1) * 10 + tile) * 1024 + lane * 16,
                      kst + ((cl + 1) & 1) * 20480 + s * 1024);
            }
        }
        int chunk = wh * 6 + cl;
        int c0 = q * 24 + 2 * chunk;
        const uint4* bl = (const uint4*)(kst + (cl & 1) * 20480 + wh * 10240);

        float u[18];
        #pragma unroll
        for (int i = 0; i < 3; ++i)
          #pragma unroll
          for (int j = 0; j < 3; ++j) {
              unsigned pr = *(const unsigned*)&us2p[((pyT + i) * 10 + pxT + j) * US_W + c0];
              u[i * 3 + j]     = bfpair_lo(pr);
              u[9 + i * 3 + j] = bfpair_hi(pr);
          }
        unsigned sp = *(const unsigned*)&us2p[hpC * US_W + c0];
        f32x4 cf[10];
        #pragma unroll
        for (int nt = 0; nt < 10; ++nt) {
            bf16x8 aW = __builtin_bit_cast(bf16x8, bl[nt * 64 + lane]);
            f32x4 z = {0.f, 0.f, 0.f, 0.f};
            cf[nt] = __builtin_amdgcn_mfma_f32_16x16x32_bf16(aW, afrag, z, 0, 0, 0);
        }
        float acc0 = cf[4][2];           // bias slots
        float acc1 = cf[9][2];
        #pragma unroll
        for (int m = 0; m < 16; ++m) {
            acc0 += cf[m >> 2][m & 3]       * u[m];
            acc1 += cf[5 + (m >> 2)][m & 3] * u[m];
        }
        acc0 += cf[4][0] * u[16] + cf[4][1] * u[17];
        acc1 += cf[9][0] * u[16] + cf[9][1] * u[17];

        float x20 = acc0 + bfpair_lo(sp);     // ga1 pre-folded into BpkA
        float x21 = acc1 + bfpair_hi(sp);
        float cv0 = greg[cl].x * x20;
        float cv1 = greg[cl].y * x21;
        cmb[chunk] = pack2bf(cv0, cv1);
        float r0 = cv0, r1 = cv1;
        #pragma unroll
        for (int s = 1; s < 16; s <<= 1) {
            r0 += __shfl_xor(r0, s, 64);
            r1 += __shfl_xor(r1, s, 64);
        }
        if (i16 == 0) {
            atomicAdd(&pooled_s[c0], r0);
            atomicAdd(&pooled_s[c0 + 1], r1);
        }
    }
    __syncthreads();
    if (tid < 96) atomicAdd(&pooled[b * HIDC + tid], pooled_s[tid]);
}

// ---------------- K2: sv (fused) + out = proj1x1( comb * sv ) ----------------
__global__ __launch_bounds__(256) void k_final(
    const unsigned* __restrict__ comb_bf, const float* __restrict__ pooled,
    const float* __restrict__ scaw, const float* __restrict__ scab,
    const float* __restrict__ projw, float* __restrict__ out)
{
    __shared__ float svs[96];
    __shared__ float cs[96][66];
    int tid = threadIdx.x;
    int blk = blockIdx.x;
    int p0 = blk * 64;
    int b = p0 >> 14;
    if (tid < 96) {
        float dot = 0.f;
        const float* pr = pooled + b * 96;
        const float* wr = scaw + tid * 96;
        #pragma unroll 4
        for (int k = 0; k < 96; ++k) dot += wr[k] * pr[k];
        svs[tid] = scab[tid] + dot * (1.0f / (float)HWP);
    }
    __syncthreads();
    for (int idx = tid; idx < 64 * 12; idx += 256) {
        int px = idx / 12, cq = idx - px * 12;
        uint4 v = *(const uint4*)&comb_bf[(size_t)(p0 + px) * 48 + cq * 4];
        int k0 = cq * 8;
        unsigned pp[4] = {v.x, v.y, v.z, v.w};
        #pragma unroll
        for (int j = 0; j < 4; ++j) {
            cs[k0 + 2*j][px]     = bfpair_lo(pp[j]) * svs[k0 + 2*j];
            cs[k0 + 2*j + 1][px] = bfpair_hi(pp[j]) * svs[k0 + 2*j + 1];
        }
    }
    __syncthreads();
    int l = tid & 63, w = tid >> 6;
    int o0 = w * 12;
    float acc[12];
    #pragma unroll
    for (int o = 0; o < 12; ++o) acc[o] = 0.f;
    #pragma unroll 4
    for (int k = 0; k < 96; ++k) {
        float v = cs[k][l];
        #pragma unroll
        for (int o = 0; o < 12; ++o)
            acc[o] += projw[(o0 + o) * 96 + k] * v;      // wave-uniform -> s_loads
    }
    float* ob = out + (size_t)b * DIMC * HWP + (p0 & 16383) + l;
    #pragma unroll
    for (int o = 0; o < 12; ++o)
        ob[(o0 + o) * HWP] = acc[o];
}

extern "C" void kernel_launch(void* const* d_in, const int* in_sizes, int n_in,
                              void* d_out, int out_size, void* d_ws, size_t ws_size,
                              hipStream_t stream)
{
    const float* x     = (const float*)d_in[0];
    const float* dw1w  = (const float*)d_in[1];
    const float* dw2w  = (const float*)d_in[2];
    const float* projw = (const float*)d_in[3];
    const float* scaw  = (const float*)d_in[4];
    const float* scab  = (const float*)d_in[5];
    const float* c1w1  = (const float*)d_in[6];
    const float* c1w2  = (const float*)d_in[7];
    const float* kbaw  = (const float*)d_in[8];
    const float* kbab  = (const float*)d_in[9];
    const float* c2w1  = (const float*)d_in[10];
    const float* c2b1  = (const float*)d_in[11];
    const float* c2w2  = (const float*)d_in[12];
    const float* c2b2  = (const float*)d_in[13];
    const float* c211w = (const float*)d_in[14];
    const float* c211b = (const float*)d_in[15];
    const float* attg  = (const float*)d_in[16];
    const float* ga1   = (const float*)d_in[17];

    unsigned* x_p     = (unsigned*)d_ws;                           // 1,572,864 dw
    unsigned* comb_bf = x_p + (size_t)BB * HWP * 24;               // 3,145,728 dw
    float* pooled     = (float*)(comb_bf + (size_t)BB * HWP * 48); // 384 f
    unsigned short* BpkA = (unsigned short*)(pooled + BB * HIDC);  // 61,440 ush
    unsigned short* Bpw  = BpkA + 61440;                           // 12,288 ush
    unsigned short* Aps  = Bpw + 12288;                            //  2,048 ush
    unsigned short* Ag   = Aps + 2048;                             //  1,024 ush

    k_prep <<<556,  256, 0, stream>>>(x, kbaw, kbab, dw1w, c1w1, ga1, c211w, c2w2, c2b2,
                                      c211b, attg, BpkA, Bpw, Aps, Ag, x_p, pooled);
    k_mff  <<<1024, dim3(64,8,1), 0, stream>>>(x_p, (const uint4*)BpkA, (const uint4*)Bpw,
                                               (const uint4*)Aps, (const uint4*)Ag,
                                               c1w2, dw2w, c2w1, c2b1, comb_bf, pooled);
    k_final<<<1024, 256, 0, stream>>>(comb_bf, pooled, scaw, scab, projw, (float*)d_out);
}

// Round 5
// 196.685 us; speedup vs baseline: 1.0826x; 1.0370x over previous
//
#include <hip/hip_runtime.h>
#include <math.h>

#define BB 4
#define HH 128
#define WW 128
#define HWP (HH*WW)
#define DIMC 48
#define HIDC 96
#define NSETC 32

// Odd-dword LDS row strides (bank-conflict fix):
#define XS_W 27     // xs row stride in dwords
#define HS_W 102    // hsw row stride in ushorts = 51 dwords
#define US_W 102    // us2p row stride in ushorts = 51 dwords

typedef __attribute__((ext_vector_type(8))) short bf16x8;
typedef __attribute__((ext_vector_type(4))) float f32x4;
typedef __attribute__((ext_vector_type(2))) float f32x2;

static __device__ __forceinline__ unsigned short f2bf(float f) {   // RNE (pack path, cold)
    union { float f; unsigned u; } v; v.f = f;
    unsigned r = (v.u + 0x7FFFu + ((v.u >> 16) & 1u)) >> 16;
    return (unsigned short)r;
}
static __device__ __forceinline__ unsigned rnd_bf(float f) {       // +0x8000 round-half-up
    union { float f; unsigned u; } v; v.f = f;
    return v.u + 0x8000u;
}
static __device__ __forceinline__ unsigned pack2bf(float lo, float hi) {
    return __builtin_amdgcn_perm(rnd_bf(hi), rnd_bf(lo), 0x07060302u);
}
static __device__ __forceinline__ void st_bf_hi(unsigned short* p, float f) {
    *p = (unsigned short)(rnd_bf(f) >> 16);
}
static __device__ __forceinline__ float bfpair_lo(unsigned pr) {
    union { unsigned u; float f; } v; v.u = pr << 16; return v.f;
}
static __device__ __forceinline__ float bfpair_hi(unsigned pr) {
    union { unsigned u; float f; } v; v.u = pr & 0xffff0000u; return v.f;
}
static __device__ __forceinline__ float gelu(float x) {
    return 0.5f * x * (1.0f + erff(x * 0.70710678118654752f));
}

// ---------------- K0: weight pack (permuted A-operand layouts) + x transpose ----------------
__global__ __launch_bounds__(256) void k_prep(
    const float* __restrict__ x,
    const float* __restrict__ kbaw, const float* __restrict__ kbab,
    const float* __restrict__ dw1w, const float* __restrict__ c1w1,
    const float* __restrict__ ga1,  const float* __restrict__ c211w,
    const float* __restrict__ c2w2, const float* __restrict__ c2b2,
    const float* __restrict__ c211b, const float* __restrict__ attg,
    unsigned short* __restrict__ Bpk, unsigned short* __restrict__ Bpw,
    unsigned short* __restrict__ Aps, unsigned short* __restrict__ Ag,
    unsigned* __restrict__ x_p, float* __restrict__ pooled)
{
    __shared__ unsigned ts[256 * 26];
    int blk = blockIdx.x, tid = threadIdx.x;
    if (blk < 300) {
        int t = blk * 256 + tid;
        if (t < 61440) {                         // BpkA
            int j = t & 7, lane = (t >> 3) & 63, tile = t >> 9;
            int chunk = tile / 10, nt = tile - chunk * 10;
            int m = lane & 15, qn = lane >> 4;
            int lc = 4 * nt + (m & 3);           // local col within this q's 40-block
            int o = lc / 20, tt = lc % 20;
            int c = (m >> 2) * 24 + 2 * chunk + o;
            int n = qn * 8 + j;
            float v = 0.f;
            if (tt < 18)       v = kbaw[n * 1728 + (c >> 1) * 36 + (c & 1) * 18 + tt] * ga1[c];
            else if (tt == 18) v = kbab[n * 96 + c] * ga1[c];
            Bpk[t] = f2bf(v);
        } else if (t < 73728) {                  // Bpw (B operand)
            int u = t - 61440;
            int s = u / 6144;
            int rem = u % 6144;
            int nt = rem >> 9;
            int lane = (rem >> 3) & 63, j = rem & 7;
            int k = s * 32 + ((lane >> 4) << 3) + j;
            int col = (nt << 4) + (lane & 15);
            float v = 0.f;
            if (k < 48) v = (col < 96) ? dw1w[col * 48 + k] : c1w1[(col - 96) * 48 + k];
            Bpw[u] = f2bf(v);
        } else if (t < 75776) {                  // Aps (skip 1x1 A-operand)
            int u = t - 73728;
            int j = u & 7, lane = (u >> 3) & 63, tile = u >> 9;   // 0..3 = kt*2+nt2
            int kt = tile >> 1, nt2 = tile & 1;
            int m = lane & 15, qn = lane >> 4;
            int n = 8 * (m >> 2) + 4 * nt2 + (m & 3);
            int k = kt * 32 + qn * 8 + j;
            Aps[u] = f2bf(k < 48 ? c211w[n * 48 + k] : 0.f);
        } else if (t < 76800) {                  // Ag (gate 1x1 A-operand, biases at k=12)
            int u = t - 75776;
            int j = u & 7, lane = (u >> 3) & 63, nt2 = u >> 9;    // 0..1
            int m = lane & 15, qn = lane >> 4;
            int n = 8 * (m >> 2) + 4 * nt2 + (m & 3);
            int k = qn * 8 + j;
            float v = 0.f;
            if (k < 12)       v = c2w2[n * 12 + k] * attg[n];
            else if (k == 12) v = c2b2[n] * attg[n] + c211b[n];
            Ag[u] = f2bf(v);
        }
    } else {
        int xblk = blk - 300;
        if (xblk == 0) {
            for (int i = tid; i < BB * HIDC; i += 256) pooled[i] = 0.f;
        }
        int b = xblk >> 6;
        int p0 = (xblk & 63) << 8;
        const float* xb = x + (size_t)b * DIMC * HWP + p0;
        #pragma unroll
        for (int c2 = 0; c2 < 24; ++c2) {
            float lo = xb[(2 * c2) * HWP + tid];
            float hi = xb[(2 * c2 + 1) * HWP + tid];
            ts[tid * 26 + c2] = pack2bf(lo, hi);
        }
        __syncthreads();
        unsigned* dst = x_p + ((size_t)b * HWP + p0) * 24;
        for (int idx = tid; idx < 256 * 24; idx += 256) {
            int px = idx / 24, j2 = idx - px * 24;
            dst[px * 24 + j2] = ts[px * 26 + j2];
        }
    }
}

// ---------------- K1 (mega-fused): att + 1x1 MFMA + depthwise + KBA -> comb(bf16) ----------------
// 1024 blocks, dim3(64,8); 2 blocks/CU (LDS ~72.7 KB) -> 4 waves/SIMD.
// Round-5: revert KBA to direct BpkA L2 loads (round-4 LDS staging: barriers cost > latency
// saved). VALU-count cuts: pk-f32x2 accumulation in att-conv and depthwise-c1 (c1w2
// relayout [tap][ch] in LDS), KBA center-tap read reuse (sp == u[4]/u[13]), split KBA
// accumulate chains (2 partials, halves dependency depth).
__global__ __launch_bounds__(512, 2) void k_mff(
    const unsigned* __restrict__ x_p,
    const uint4* __restrict__ BpkA, const uint4* __restrict__ Bpw,
    const uint4* __restrict__ Aps,  const uint4* __restrict__ Ag,
    const float* __restrict__ c1w2, const float* __restrict__ dw2w,
    const float* __restrict__ c2w1, const float* __restrict__ c2b1,
    unsigned* __restrict__ comb_bf, float* __restrict__ pooled)
{
    __shared__ __attribute__((aligned(16))) unsigned xs[144 * XS_W];        // x halo 12x12 (15.2 KB)
    __shared__ __attribute__((aligned(16))) unsigned short hsw[144 * HS_W]; // h tiles ; aliased att_t (28.7 KB)
    __shared__ __attribute__((aligned(16))) unsigned short us2p[100 * US_W];// uf halo (19.9 KB)
    __shared__ __attribute__((aligned(16))) float wls[864 + 432 + 24];      // dw2w | c2w1 | c2b1 (5.3 KB)
    __shared__ __attribute__((aligned(16))) float c1s[864];                 // c1w2 relayout [tap][96] (3.5 KB)
    __shared__ float pooled_s[96];

    int lane = threadIdx.x, wy = threadIdx.y;   // wy 0..7
    int tid = wy * 64 + lane;
    int blk = blockIdx.x;
    int b = blk >> 8, ty = (blk >> 4) & 15, tx = blk & 15;
    int q = lane >> 4, i16 = lane & 15;
    int wh = wy >> 2;          // channel/chunk half (0/1)
    int wp = wy & 3;           // pixel group 0..3

    float* wats  = wls + 864;    // [g][tap][2]
    float* c2b1s = wls + 864 + 432;
    float* att_tf = (float*)hsw; // [px(64)][XS_W] floats, lives before PASS A

    // ---- stage: xs / weight tables / pooled_s ----
    if (tid < 96) pooled_s[tid] = 0.f;
    for (int idx = tid; idx < 864; idx += 512) {
        int t5 = idx / 96, c = idx - t5 * 96;
        wls[idx] = dw2w[c * 9 + t5];
        c1s[idx] = c1w2[c * 9 + t5];
    }
    for (int idx = tid; idx < 216; idx += 512) {
        int g = idx / 9, tap = idx - g * 9;
        wats[idx * 2]     = c2w1[g * 18 + tap];
        wats[idx * 2 + 1] = c2w1[g * 18 + 9 + tap];
    }
    if (tid < 24) c2b1s[tid] = c2b1[tid];
    for (int idx = tid; idx < 144 * 12; idx += 512) {
        int pos = idx / 12, jp = idx - pos * 12;
        int gy = ty * 8 - 2 + pos / 12, gx = tx * 8 - 2 + pos % 12;
        uint2 v = {0u, 0u};
        if (((unsigned)gy < (unsigned)HH) & ((unsigned)gx < (unsigned)WW))
            v = *(const uint2*)&x_p[((size_t)b * HWP + gy * WW + gx) * 24 + jp * 2];
        xs[pos * XS_W + jp * 2]     = v.x;
        xs[pos * XS_W + jp * 2 + 1] = v.y;
    }
    __syncthreads();

    int p_t = wp * 16 + i16;
    int pyT = p_t >> 3, pxT = p_t & 7;
    int gp = (ty * 8 + pyT) * WW + tx * 8 + pxT;
    uint4 z4 = {0u, 0u, 0u, 0u};

    // ---- att: grouped conv t (8 threads/pixel across wave pair, 3 groups each) ----
    #pragma unroll
    for (int ci = 0; ci < 3; ++ci) {
        int g = q * 6 + wh * 3 + ci;
        f32x2 av = {0.f, 0.f};
        #pragma unroll
        for (int di = 0; di < 3; ++di)
          #pragma unroll
          for (int dj = 0; dj < 3; ++dj) {
              unsigned pr = xs[((pyT + 1 + di) * 12 + pxT + 1 + dj) * XS_W + g];
              f32x2 w2 = *(const f32x2*)&wats[(g * 9 + di * 3 + dj) * 2];
              f32x2 hv = {bfpair_lo(pr), bfpair_hi(pr)};
              av += w2 * hv;                       // v_pk_fma_f32
          }
        att_tf[p_t * XS_W + g] = c2b1s[g] + av.x + av.y;
    }
    __syncthreads();

    // ---- att: gate + skip via permuted-A MFMA -> afrag in registers ----
    bf16x8 afrag;
    {
        int p26 = p_t * XS_W;
        unsigned tgd[4];
        #pragma unroll
        for (int i2 = 0; i2 < 4; ++i2) {
            int k0 = q * 8 + 2 * i2;
            int k1 = k0 + 1;
            float v0 = (k0 < 12) ? att_tf[p26 + k0] * att_tf[p26 + 12 + k0] : (k0 == 12 ? 1.f : 0.f);
            float v1 = (k1 < 12) ? att_tf[p26 + k1] * att_tf[p26 + 12 + k1] : (k1 == 12 ? 1.f : 0.f);
            tgd[i2] = pack2bf(v0, v1);
        }
        uint4 tgr = {tgd[0], tgd[1], tgd[2], tgd[3]};
        bf16x8 btg = __builtin_bit_cast(bf16x8, tgr);

        int cen = (pyT + 2) * 12 + (pxT + 2);
        int cb = cen * XS_W + q * 4;
        uint4 bx0r = {xs[cb], xs[cb + 1], xs[cb + 2], xs[cb + 3]};
        uint4 bx1r = z4;                // MUST be zeroed for q>=2: xs entries 24+ are
        if (q < 2) {                    // unwritten garbage; 0-weight x NaN = NaN
            int cb2 = cen * XS_W + 16 + q * 4;
            bx1r.x = xs[cb2]; bx1r.y = xs[cb2 + 1]; bx1r.z = xs[cb2 + 2]; bx1r.w = xs[cb2 + 3];
        }
        bf16x8 bx0 = __builtin_bit_cast(bf16x8, bx0r);
        bf16x8 bx1 = __builtin_bit_cast(bf16x8, bx1r);

        float attv[8];
        #pragma unroll
        for (int nt2 = 0; nt2 < 2; ++nt2) {
            bf16x8 ag  = __builtin_bit_cast(bf16x8, Ag[nt2 * 64 + lane]);
            bf16x8 as0 = __builtin_bit_cast(bf16x8, Aps[nt2 * 64 + lane]);
            bf16x8 as1 = __builtin_bit_cast(bf16x8, Aps[(2 + nt2) * 64 + lane]);
            f32x4 z = {0.f, 0.f, 0.f, 0.f};
            f32x4 c = __builtin_amdgcn_mfma_f32_16x16x32_bf16(ag, btg, z, 0, 0, 0);
            c = __builtin_amdgcn_mfma_f32_16x16x32_bf16(as1, bx1, c, 0, 0, 0);
            c = __builtin_amdgcn_mfma_f32_16x16x32_bf16(as0, bx0, c, 0, 0, 0);
            #pragma unroll
            for (int r = 0; r < 4; ++r) attv[nt2 * 4 + r] = c[r];
        }
        uint4 au = {pack2bf(attv[0], attv[1]), pack2bf(attv[2], attv[3]),
                    pack2bf(attv[4], attv[5]), pack2bf(attv[6], attv[7])};
        afrag = __builtin_bit_cast(bf16x8, au);
    }
    __syncthreads();   // att_tf dead -> hsw free for PASS A

    // ========== PASS A: h(c1) on 12x12 halo via MFMA ==========
    // Each wave: own rg (6 nt). rg8's 6 nt-tiles spread one-each over waves 1..6.
    {
        {
            int rg = wy;
            int hp = rg * 16 + i16;
            int ab = hp * XS_W + q * 4;
            uint4 a0r = {xs[ab], xs[ab + 1], xs[ab + 2], xs[ab + 3]};
            uint4 a1r = z4;
            if (q < 2) {
                int ab2 = hp * XS_W + 16 + q * 4;
                a1r.x = xs[ab2]; a1r.y = xs[ab2 + 1]; a1r.z = xs[ab2 + 2]; a1r.w = xs[ab2 + 3];
            }
            bf16x8 a0 = __builtin_bit_cast(bf16x8, a0r);
            bf16x8 a1 = __builtin_bit_cast(bf16x8, a1r);
            int rowb = rg * 16 + 4 * q;
            #pragma unroll
            for (int nt = 0; nt < 6; ++nt) {
                bf16x8 b0 = __builtin_bit_cast(bf16x8, Bpw[(size_t)((6 + nt) << 6) + lane]);
                bf16x8 b1 = __builtin_bit_cast(bf16x8, Bpw[(size_t)((18 + nt) << 6) + lane]);
                f32x4 z = {0.f, 0.f, 0.f, 0.f};
                f32x4 c = __builtin_amdgcn_mfma_f32_16x16x32_bf16(a1, b1, z, 0, 0, 0);
                c = __builtin_amdgcn_mfma_f32_16x16x32_bf16(a0, b0, c, 0, 0, 0);
                #pragma unroll
                for (int r = 0; r < 4; ++r)
                    st_bf_hi(&hsw[(rowb + r) * HS_W + nt * 16 + i16], c[r]);
            }
        }
        if (wy >= 1 && wy <= 6) {                 // rg8, one nt-tile per wave
            int hp = 128 + i16;
            int ab = hp * XS_W + q * 4;
            uint4 a0r = {xs[ab], xs[ab + 1], xs[ab + 2], xs[ab + 3]};
            uint4 a1r = z4;
            if (q < 2) {
                int ab2 = hp * XS_W + 16 + q * 4;
                a1r.x = xs[ab2]; a1r.y = xs[ab2 + 1]; a1r.z = xs[ab2 + 2]; a1r.w = xs[ab2 + 3];
            }
            bf16x8 a0 = __builtin_bit_cast(bf16x8, a0r);
            bf16x8 a1 = __builtin_bit_cast(bf16x8, a1r);
            int rowb = 128 + 4 * q;
            int nt = wy - 1;
            bf16x8 b0 = __builtin_bit_cast(bf16x8, Bpw[(size_t)((6 + nt) << 6) + lane]);
            bf16x8 b1 = __builtin_bit_cast(bf16x8, Bpw[(size_t)((18 + nt) << 6) + lane]);
            f32x4 z = {0.f, 0.f, 0.f, 0.f};
            f32x4 c = __builtin_amdgcn_mfma_f32_16x16x32_bf16(a1, b1, z, 0, 0, 0);
            c = __builtin_amdgcn_mfma_f32_16x16x32_bf16(a0, b0, c, 0, 0, 0);
            #pragma unroll
            for (int r = 0; r < 4; ++r)
                st_bf_hi(&hsw[(rowb + r) * HS_W + nt * 16 + i16], c[r]);
        }
    }
    __syncthreads();

    // ---- depthwise c1 -> uf on 10x10 halo (us2p): 24 (cq,half) sub-units over 8 waves ----
    #pragma unroll 1
    for (int it = 0; it < 3; ++it) {
        int su = wy * 3 + it;                  // 0..23
        int cq = su >> 1;                      // wave-uniform
        int hp2 = (su & 1) * 50 + lane;
        if (lane < 50) {
            int py2 = hp2 / 10, px2 = hp2 - py2 * 10;
            f32x2 a2[4];
            #pragma unroll
            for (int c = 0; c < 4; ++c) a2[c] = (f32x2){0.f, 0.f};
            #pragma unroll
            for (int di = 0; di < 3; ++di)
              #pragma unroll
              for (int dj = 0; dj < 3; ++dj) {
                  int rb = ((py2 + di) * 12 + px2 + dj) * HS_W + cq * 8;
                  unsigned pp[4];
                  pp[0] = *(const unsigned*)&hsw[rb];
                  pp[1] = *(const unsigned*)&hsw[rb + 2];
                  pp[2] = *(const unsigned*)&hsw[rb + 4];
                  pp[3] = *(const unsigned*)&hsw[rb + 6];
                  const f32x2* wrow = (const f32x2*)&c1s[(di * 3 + dj) * 96 + cq * 8];
                  #pragma unroll
                  for (int c2 = 0; c2 < 4; ++c2) {
                      f32x2 hv = {bfpair_lo(pp[c2]), bfpair_hi(pp[c2])};
                      a2[c2] += wrow[c2] * hv;         // v_pk_fma_f32
                  }
              }
            int wb = hp2 * US_W + cq * 8;
            *(unsigned*)&us2p[wb]     = pack2bf(a2[0].x, a2[0].y);
            *(unsigned*)&us2p[wb + 2] = pack2bf(a2[1].x, a2[1].y);
            *(unsigned*)&us2p[wb + 4] = pack2bf(a2[2].x, a2[2].y);
            *(unsigned*)&us2p[wb + 6] = pack2bf(a2[3].x, a2[3].y);
        }
    }
    __syncthreads();

    // ========== PASS B: h(dw) on 10x10 halo via MFMA (7 row-groups, 1 per wave) ==========
    if (wy < 7) {
        int rg = wy;
        int hp = rg * 16 + i16;
        bool okp = hp < 100;
        int hy = hp / 10, hx = hp - hy * 10;
        int pos = okp ? ((hy + 1) * 12 + hx + 1) : 0;
        int ab = pos * XS_W + q * 4;
        uint4 a0r = {xs[ab], xs[ab + 1], xs[ab + 2], xs[ab + 3]};
        uint4 a1r = z4;
        if (q < 2) {
            int ab2 = pos * XS_W + 16 + q * 4;
            a1r.x = xs[ab2]; a1r.y = xs[ab2 + 1]; a1r.z = xs[ab2 + 2]; a1r.w = xs[ab2 + 3];
        }
        bf16x8 a0 = __builtin_bit_cast(bf16x8, a0r);
        bf16x8 a1 = __builtin_bit_cast(bf16x8, a1r);
        int rowb = rg * 16 + 4 * q;
        #pragma unroll
        for (int nt = 0; nt < 6; ++nt) {
            bf16x8 b0 = __builtin_bit_cast(bf16x8, Bpw[(size_t)(nt << 6) + lane]);
            bf16x8 b1 = __builtin_bit_cast(bf16x8, Bpw[(size_t)((12 + nt) << 6) + lane]);
            f32x4 z = {0.f, 0.f, 0.f, 0.f};
            f32x4 c = __builtin_amdgcn_mfma_f32_16x16x32_bf16(a1, b1, z, 0, 0, 0);
            c = __builtin_amdgcn_mfma_f32_16x16x32_bf16(a0, b0, c, 0, 0, 0);
            #pragma unroll
            for (int r = 0; r < 4; ++r)
                st_bf_hi(&hsw[(rowb + r) * HS_W + nt * 16 + i16], c[r]);  // rows>=100 harmless
        }
    }
    __syncthreads();

    // ---- depthwise dw -> gelu(x1) for OWN pixel, 12 channels (this wave's half) ----
    f32x2 greg[6];
    {
        int base = q * 24 + wh * 12;
        #pragma unroll
        for (int cc = 0; cc < 6; ++cc) {
            int c0 = base + 2 * cc;
            f32x2 acc = {0.f, 0.f};
            #pragma unroll
            for (int di = 0; di < 3; ++di)
              #pragma unroll
              for (int dj = 0; dj < 3; ++dj) {
                  unsigned pr = *(const unsigned*)&hsw[((pyT + di) * 10 + pxT + dj) * HS_W + c0];
                  f32x2 hv = {bfpair_lo(pr), bfpair_hi(pr)};
                  f32x2 wv = *(const f32x2*)&wls[(di * 3 + dj) * 96 + c0];
                  acc += wv * hv;
              }
            greg[cc].x = gelu(acc.x);
            greg[cc].y = gelu(acc.y);
        }
    }
    // no barrier needed: KBA never writes hsw

    // ========== KBA: permuted-A MFMA, 6 chunks per wave (wave pair splits 12) ==========
    unsigned* cmb = comb_bf + ((size_t)b * HWP + gp) * 48 + q * 12;

    #pragma unroll
    for (int cl = 0; cl < 6; ++cl) {
        int chunk = wh * 6 + cl;
        int c0 = q * 24 + 2 * chunk;
        // issue LDS reads early so they overlap the MFMA cluster
        float u[18];
        #pragma unroll
        for (int i = 0; i < 3; ++i)
          #pragma unroll
          for (int j = 0; j < 3; ++j) {
              unsigned pr = *(const unsigned*)&us2p[((pyT + i) * 10 + pxT + j) * US_W + c0];
              u[i * 3 + j]     = bfpair_lo(pr);
              u[9 + i * 3 + j] = bfpair_hi(pr);
          }
        f32x4 cf[10];
        #pragma unroll
        for (int nt = 0; nt < 10; ++nt) {
            bf16x8 aW = __builtin_bit_cast(bf16x8, BpkA[(size_t)((chunk * 10 + nt) << 6) + lane]);
            f32x4 z = {0.f, 0.f, 0.f, 0.f};
            cf[nt] = __builtin_amdgcn_mfma_f32_16x16x32_bf16(aW, afrag, z, 0, 0, 0);
        }
        // split accumulate chains (2 partials each) to halve dependency depth
        float s0a = cf[4][2], s1a = cf[9][2];
        float s0b = 0.f,      s1b = 0.f;
        #pragma unroll
        for (int m = 0; m < 8; ++m) {
            s0a += cf[m >> 2][m & 3]       * u[m];
            s1a += cf[5 + (m >> 2)][m & 3] * u[m];
        }
        #pragma unroll
        for (int m = 8; m < 16; ++m) {
            s0b += cf[m >> 2][m & 3]       * u[m];
            s1b += cf[5 + (m >> 2)][m & 3] * u[m];
        }
        s0b += cf[4][0] * u[16] + cf[4][1] * u[17];
        s1b += cf[9][0] * u[16] + cf[9][1] * u[17];

        float x20 = (s0a + s0b) + u[4];       // skip-add: center tap == u[4]/u[13]
        float x21 = (s1a + s1b) + u[13];      // (ga1 pre-folded into BpkA)
        float cv0 = greg[cl].x * x20;
        float cv1 = greg[cl].y * x21;
        cmb[chunk] = pack2bf(cv0, cv1);
        float r0 = cv0, r1 = cv1;
        #pragma unroll
        for (int s = 1; s < 16; s <<= 1) {
            r0 += __shfl_xor(r0, s, 64);
            r1 += __shfl_xor(r1, s, 64);
        }
        if (i16 == 0) {
            atomicAdd(&pooled_s[c0], r0);
            atomicAdd(&pooled_s[c0 + 1], r1);
        }
    }
    __syncthreads();
    if (tid < 96) atomicAdd(&pooled[b * HIDC + tid], pooled_s[tid]);
}

// ---------------- K2: sv (fused) + out = proj1x1( comb * sv ) ----------------
__global__ __launch_bounds__(256) void k_final(
    const unsigned* __restrict__ comb_bf, const float* __restrict__ pooled,
    const float* __restrict__ scaw, const float* __restrict__ scab,
    const float* __restrict__ projw, float* __restrict__ out)
{
    __shared__ float svs[96];
    __shared__ float cs[96][66];
    int tid = threadIdx.x;
    int blk = blockIdx.x;
    int p0 = blk * 64;
    int b = p0 >> 14;
    if (tid < 96) {
        float dot = 0.f;
        const float* pr = pooled + b * 96;
        const float* wr = scaw + tid * 96;
        #pragma unroll 4
        for (int k = 0; k < 96; ++k) dot += wr[k] * pr[k];
        svs[tid] = scab[tid] + dot * (1.0f / (float)HWP);
    }
    __syncthreads();
    for (int idx = tid; idx < 64 * 12; idx += 256) {
        int px = idx / 12, cq = idx - px * 12;
        uint4 v = *(const uint4*)&comb_bf[(size_t)(p0 + px) * 48 + cq * 4];
        int k0 = cq * 8;
        unsigned pp[4] = {v.x, v.y, v.z, v.w};
        #pragma unroll
        for (int j = 0; j < 4; ++j) {
            cs[k0 + 2*j][px]     = bfpair_lo(pp[j]) * svs[k0 + 2*j];
            cs[k0 + 2*j + 1][px] = bfpair_hi(pp[j]) * svs[k0 + 2*j + 1];
        }
    }
    __syncthreads();
    int l = tid & 63, w = tid >> 6;
    int o0 = w * 12;
    float acc[12];
    #pragma unroll
    for (int o = 0; o < 12; ++o) acc[o] = 0.f;
    #pragma unroll 4
    for (int k = 0; k < 96; ++k) {
        float v = cs[k][l];
        #pragma unroll
        for (int o = 0; o < 12; ++o)
            acc[o] += projw[(o0 + o) * 96 + k] * v;      // wave-uniform -> s_loads
    }
    float* ob = out + (size_t)b * DIMC * HWP + (p0 & 16383) + l;
    #pragma unroll
    for (int o = 0; o < 12; ++o)
        ob[(o0 + o) * HWP] = acc[o];
}

extern "C" void kernel_launch(void* const* d_in, const int* in_sizes, int n_in,
                              void* d_out, int out_size, void* d_ws, size_t ws_size,
                              hipStream_t stream)
{
    const float* x     = (const float*)d_in[0];
    const float* dw1w  = (const float*)d_in[1];
    const float* dw2w  = (const float*)d_in[2];
    const float* projw = (const float*)d_in[3];
    const float* scaw  = (const float*)d_in[4];
    const float* scab  = (const float*)d_in[5];
    const float* c1w1  = (const float*)d_in[6];
    const float* c1w2  = (const float*)d_in[7];
    const float* kbaw  = (const float*)d_in[8];
    const float* kbab  = (const float*)d_in[9];
    const float* c2w1  = (const float*)d_in[10];
    const float* c2b1  = (const float*)d_in[11];
    const float* c2w2  = (const float*)d_in[12];
    const float* c2b2  = (const float*)d_in[13];
    const float* c211w = (const float*)d_in[14];
    const float* c211b = (const float*)d_in[15];
    const float* attg  = (const float*)d_in[16];
    const float* ga1   = (const float*)d_in[17];

    unsigned* x_p     = (unsigned*)d_ws;                           // 1,572,864 dw
    unsigned* comb_bf = x_p + (size_t)BB * HWP * 24;               // 3,145,728 dw
    float* pooled     = (float*)(comb_bf + (size_t)BB * HWP * 48); // 384 f
    unsigned short* BpkA = (unsigned short*)(pooled + BB * HIDC);  // 61,440 ush
    unsigned short* Bpw  = BpkA + 61440;                           // 12,288 ush
    unsigned short* Aps  = Bpw + 12288;                            //  2,048 ush
    unsigned short* Ag   = Aps + 2048;                             //  1,024 ush

    k_prep <<<556,  256, 0, stream>>>(x, kbaw, kbab, dw1w, c1w1, ga1, c211w, c2w2, c2b2,
                                      c211b, attg, BpkA, Bpw, Aps, Ag, x_p, pooled);
    k_mff  <<<1024, dim3(64,8,1), 0, stream>>>(x_p, (const uint4*)BpkA, (const uint4*)Bpw,
                                               (const uint4*)Aps, (const uint4*)Ag,
                                               c1w2, dw2w, c2w1, c2b1, comb_bf, pooled);
    k_final<<<1024, 256, 0, stream>>>(comb_bf, pooled, scaw, scab, projw, (float*)d_out);
}

// Round 6
// 194.732 us; speedup vs baseline: 1.0934x; 1.0100x over previous
//
#include <hip/hip_runtime.h>
#include <math.h>

#define BB 4
#define HH 128
#define WW 128
#define HWP (HH*WW)
#define DIMC 48
#define HIDC 96
#define NSETC 32

// Odd-dword LDS row strides (bank-conflict fix):
#define XS_W 27     // xs row stride in dwords
#define HS_W 102    // hsw row stride in ushorts = 51 dwords
#define US_W 102    // us2p row stride in ushorts = 51 dwords

typedef __attribute__((ext_vector_type(8))) short bf16x8;
typedef __attribute__((ext_vector_type(4))) float f32x4;
typedef __attribute__((ext_vector_type(2))) float f32x2;

static __device__ __forceinline__ unsigned short f2bf(float f) {   // RNE (pack path, cold)
    union { float f; unsigned u; } v; v.f = f;
    unsigned r = (v.u + 0x7FFFu + ((v.u >> 16) & 1u)) >> 16;
    return (unsigned short)r;
}
static __device__ __forceinline__ unsigned rnd_bf(float f) {       // +0x8000 round-half-up
    union { float f; unsigned u; } v; v.f = f;
    return v.u + 0x8000u;
}
static __device__ __forceinline__ unsigned pack2bf(float lo, float hi) {
    return __builtin_amdgcn_perm(rnd_bf(hi), rnd_bf(lo), 0x07060302u);
}
static __device__ __forceinline__ void st_bf_hi(unsigned short* p, float f) {
    *p = (unsigned short)(rnd_bf(f) >> 16);
}
static __device__ __forceinline__ float bfpair_lo(unsigned pr) {
    union { unsigned u; float f; } v; v.u = pr << 16; return v.f;
}
static __device__ __forceinline__ float bfpair_hi(unsigned pr) {
    union { unsigned u; float f; } v; v.u = pr & 0xffff0000u; return v.f;
}
static __device__ __forceinline__ float gelu(float x) {
    return 0.5f * x * (1.0f + erff(x * 0.70710678118654752f));
}

// ---------------- K0: weight pack (permuted A-operand layouts) + x transpose ----------------
__global__ __launch_bounds__(256) void k_prep(
    const float* __restrict__ x,
    const float* __restrict__ kbaw, const float* __restrict__ kbab,
    const float* __restrict__ dw1w, const float* __restrict__ c1w1,
    const float* __restrict__ ga1,  const float* __restrict__ c211w,
    const float* __restrict__ c2w2, const float* __restrict__ c2b2,
    const float* __restrict__ c211b, const float* __restrict__ attg,
    unsigned short* __restrict__ Bpk, unsigned short* __restrict__ Bpw,
    unsigned short* __restrict__ Aps, unsigned short* __restrict__ Ag,
    unsigned* __restrict__ x_p, float* __restrict__ pooled)
{
    __shared__ unsigned ts[256 * 26];
    int blk = blockIdx.x, tid = threadIdx.x;
    if (blk < 300) {
        int t = blk * 256 + tid;
        if (t < 61440) {                         // BpkA
            int j = t & 7, lane = (t >> 3) & 63, tile = t >> 9;
            int chunk = tile / 10, nt = tile - chunk * 10;
            int m = lane & 15, qn = lane >> 4;
            int lc = 4 * nt + (m & 3);           // local col within this q's 40-block
            int o = lc / 20, tt = lc % 20;
            int c = (m >> 2) * 24 + 2 * chunk + o;
            int n = qn * 8 + j;
            float v = 0.f;
            if (tt < 18)       v = kbaw[n * 1728 + (c >> 1) * 36 + (c & 1) * 18 + tt] * ga1[c];
            else if (tt == 18) v = kbab[n * 96 + c] * ga1[c];
            Bpk[t] = f2bf(v);
        } else if (t < 73728) {                  // Bpw (B operand)
            int u = t - 61440;
            int s = u / 6144;
            int rem = u % 6144;
            int nt = rem >> 9;
            int lane = (rem >> 3) & 63, j = rem & 7;
            int k = s * 32 + ((lane >> 4) << 3) + j;
            int col = (nt << 4) + (lane & 15);
            float v = 0.f;
            if (k < 48) v = (col < 96) ? dw1w[col * 48 + k] : c1w1[(col - 96) * 48 + k];
            Bpw[u] = f2bf(v);
        } else if (t < 75776) {                  // Aps (skip 1x1 A-operand)
            int u = t - 73728;
            int j = u & 7, lane = (u >> 3) & 63, tile = u >> 9;   // 0..3 = kt*2+nt2
            int kt = tile >> 1, nt2 = tile & 1;
            int m = lane & 15, qn = lane >> 4;
            int n = 8 * (m >> 2) + 4 * nt2 + (m & 3);
            int k = kt * 32 + qn * 8 + j;
            Aps[u] = f2bf(k < 48 ? c211w[n * 48 + k] : 0.f);
        } else if (t < 76800) {                  // Ag (gate 1x1 A-operand, biases at k=12)
            int u = t - 75776;
            int j = u & 7, lane = (u >> 3) & 63, nt2 = u >> 9;    // 0..1
            int m = lane & 15, qn = lane >> 4;
            int n = 8 * (m >> 2) + 4 * nt2 + (m & 3);
            int k = qn * 8 + j;
            float v = 0.f;
            if (k < 12)       v = c2w2[n * 12 + k] * attg[n];
            else if (k == 12) v = c2b2[n] * attg[n] + c211b[n];
            Ag[u] = f2bf(v);
        }
    } else {
        int xblk = blk - 300;
        if (xblk == 0) {
            for (int i = tid; i < BB * HIDC; i += 256) pooled[i] = 0.f;
        }
        int b = xblk >> 6;
        int p0 = (xblk & 63) << 8;
        const float* xb = x + (size_t)b * DIMC * HWP + p0;
        #pragma unroll
        for (int c2 = 0; c2 < 24; ++c2) {
            float lo = xb[(2 * c2) * HWP + tid];
            float hi = xb[(2 * c2 + 1) * HWP + tid];
            ts[tid * 26 + c2] = pack2bf(lo, hi);
        }
        __syncthreads();
        unsigned* dst = x_p + ((size_t)b * HWP + p0) * 24;
        for (int idx = tid; idx < 256 * 24; idx += 256) {
            int px = idx / 24, j2 = idx - px * 24;
            dst[px * 24 + j2] = ts[px * 26 + j2];
        }
    }
}

// ---------------- K1 (mega-fused): att + 1x1 MFMA + depthwise + KBA -> comb(bf16) ----------------
// 1024 blocks, dim3(64,8); 2 blocks/CU (LDS ~72.7 KB) -> 4 waves/SIMD.
// Round-6: (1) att_tf aliases us2p (not hsw) -> the afrag->PASSA barrier is deleted (7->6
// barriers; dwc1's existing barrier covers the us2p overwrite). (2) KBA pooled shfl-tree
// reductions deferred to after the chunk loop (12 independent chains instead of 6 serial
// ones on the chunk critical path). (3) comb store vectorized: 6 b32 -> 3 uint2 at the
// contiguous cmb+wh*6 (8B aligned).
__global__ __launch_bounds__(512, 2) void k_mff(
    const unsigned* __restrict__ x_p,
    const uint4* __restrict__ BpkA, const uint4* __restrict__ Bpw,
    const uint4* __restrict__ Aps,  const uint4* __restrict__ Ag,
    const float* __restrict__ c1w2, const float* __restrict__ dw2w,
    const float* __restrict__ c2w1, const float* __restrict__ c2b1,
    unsigned* __restrict__ comb_bf, float* __restrict__ pooled)
{
    __shared__ __attribute__((aligned(16))) unsigned xs[144 * XS_W];        // x halo 12x12 (15.2 KB)
    __shared__ __attribute__((aligned(16))) unsigned short hsw[144 * HS_W]; // h tiles (28.7 KB)
    __shared__ __attribute__((aligned(16))) unsigned short us2p[100 * US_W];// uf halo ; aliased att_t (19.9 KB)
    __shared__ __attribute__((aligned(16))) float wls[864 + 432 + 24];      // dw2w | c2w1 | c2b1 (5.3 KB)
    __shared__ __attribute__((aligned(16))) float c1s[864];                 // c1w2 relayout [tap][96] (3.5 KB)
    __shared__ float pooled_s[96];

    int lane = threadIdx.x, wy = threadIdx.y;   // wy 0..7
    int tid = wy * 64 + lane;
    int blk = blockIdx.x;
    int b = blk >> 8, ty = (blk >> 4) & 15, tx = blk & 15;
    int q = lane >> 4, i16 = lane & 15;
    int wh = wy >> 2;          // channel/chunk half (0/1)
    int wp = wy & 3;           // pixel group 0..3

    float* wats  = wls + 864;    // [g][tap][2]
    float* c2b1s = wls + 864 + 432;
    float* att_tf = (float*)us2p; // [px(64)][XS_W] floats; us2p fully rewritten later by dwc1

    // ---- stage: xs / weight tables / pooled_s ----
    if (tid < 96) pooled_s[tid] = 0.f;
    for (int idx = tid; idx < 864; idx += 512) {
        int t5 = idx / 96, c = idx - t5 * 96;
        wls[idx] = dw2w[c * 9 + t5];
        c1s[idx] = c1w2[c * 9 + t5];
    }
    for (int idx = tid; idx < 216; idx += 512) {
        int g = idx / 9, tap = idx - g * 9;
        wats[idx * 2]     = c2w1[g * 18 + tap];
        wats[idx * 2 + 1] = c2w1[g * 18 + 9 + tap];
    }
    if (tid < 24) c2b1s[tid] = c2b1[tid];
    for (int idx = tid; idx < 144 * 12; idx += 512) {
        int pos = idx / 12, jp = idx - pos * 12;
        int gy = ty * 8 - 2 + pos / 12, gx = tx * 8 - 2 + pos % 12;
        uint2 v = {0u, 0u};
        if (((unsigned)gy < (unsigned)HH) & ((unsigned)gx < (unsigned)WW))
            v = *(const uint2*)&x_p[((size_t)b * HWP + gy * WW + gx) * 24 + jp * 2];
        xs[pos * XS_W + jp * 2]     = v.x;
        xs[pos * XS_W + jp * 2 + 1] = v.y;
    }
    __syncthreads();

    int p_t = wp * 16 + i16;
    int pyT = p_t >> 3, pxT = p_t & 7;
    int gp = (ty * 8 + pyT) * WW + tx * 8 + pxT;
    uint4 z4 = {0u, 0u, 0u, 0u};

    // ---- att: grouped conv t (8 threads/pixel across wave pair, 3 groups each) ----
    #pragma unroll
    for (int ci = 0; ci < 3; ++ci) {
        int g = q * 6 + wh * 3 + ci;
        f32x2 av = {0.f, 0.f};
        #pragma unroll
        for (int di = 0; di < 3; ++di)
          #pragma unroll
          for (int dj = 0; dj < 3; ++dj) {
              unsigned pr = xs[((pyT + 1 + di) * 12 + pxT + 1 + dj) * XS_W + g];
              f32x2 w2 = *(const f32x2*)&wats[(g * 9 + di * 3 + dj) * 2];
              f32x2 hv = {bfpair_lo(pr), bfpair_hi(pr)};
              av += w2 * hv;                       // v_pk_fma_f32
          }
        att_tf[p_t * XS_W + g] = c2b1s[g] + av.x + av.y;
    }
    __syncthreads();

    // ---- att: gate + skip via permuted-A MFMA -> afrag in registers ----
    bf16x8 afrag;
    {
        int p26 = p_t * XS_W;
        unsigned tgd[4];
        #pragma unroll
        for (int i2 = 0; i2 < 4; ++i2) {
            int k0 = q * 8 + 2 * i2;
            int k1 = k0 + 1;
            float v0 = (k0 < 12) ? att_tf[p26 + k0] * att_tf[p26 + 12 + k0] : (k0 == 12 ? 1.f : 0.f);
            float v1 = (k1 < 12) ? att_tf[p26 + k1] * att_tf[p26 + 12 + k1] : (k1 == 12 ? 1.f : 0.f);
            tgd[i2] = pack2bf(v0, v1);
        }
        uint4 tgr = {tgd[0], tgd[1], tgd[2], tgd[3]};
        bf16x8 btg = __builtin_bit_cast(bf16x8, tgr);

        int cen = (pyT + 2) * 12 + (pxT + 2);
        int cb = cen * XS_W + q * 4;
        uint4 bx0r = {xs[cb], xs[cb + 1], xs[cb + 2], xs[cb + 3]};
        uint4 bx1r = z4;                // MUST be zeroed for q>=2: xs entries 24+ are
        if (q < 2) {                    // unwritten garbage; 0-weight x NaN = NaN
            int cb2 = cen * XS_W + 16 + q * 4;
            bx1r.x = xs[cb2]; bx1r.y = xs[cb2 + 1]; bx1r.z = xs[cb2 + 2]; bx1r.w = xs[cb2 + 3];
        }
        bf16x8 bx0 = __builtin_bit_cast(bf16x8, bx0r);
        bf16x8 bx1 = __builtin_bit_cast(bf16x8, bx1r);

        float attv[8];
        #pragma unroll
        for (int nt2 = 0; nt2 < 2; ++nt2) {
            bf16x8 ag  = __builtin_bit_cast(bf16x8, Ag[nt2 * 64 + lane]);
            bf16x8 as0 = __builtin_bit_cast(bf16x8, Aps[nt2 * 64 + lane]);
            bf16x8 as1 = __builtin_bit_cast(bf16x8, Aps[(2 + nt2) * 64 + lane]);
            f32x4 z = {0.f, 0.f, 0.f, 0.f};
            f32x4 c = __builtin_amdgcn_mfma_f32_16x16x32_bf16(ag, btg, z, 0, 0, 0);
            c = __builtin_amdgcn_mfma_f32_16x16x32_bf16(as1, bx1, c, 0, 0, 0);
            c = __builtin_amdgcn_mfma_f32_16x16x32_bf16(as0, bx0, c, 0, 0, 0);
            #pragma unroll
            for (int r = 0; r < 4; ++r) attv[nt2 * 4 + r] = c[r];
        }
        uint4 au = {pack2bf(attv[0], attv[1]), pack2bf(attv[2], attv[3]),
                    pack2bf(attv[4], attv[5]), pack2bf(attv[6], attv[7])};
        afrag = __builtin_bit_cast(bf16x8, au);
    }
    // NO barrier: att_tf lives in us2p now; PASS A touches only hsw/xs. The next us2p
    // write (dwc1) is behind the PASS A -> dwc1 barrier.

    // ========== PASS A: h(c1) on 12x12 halo via MFMA ==========
    // Each wave: own rg (6 nt). rg8's 6 nt-tiles spread one-each over waves 1..6.
    {
        {
            int rg = wy;
            int hp = rg * 16 + i16;
            int ab = hp * XS_W + q * 4;
            uint4 a0r = {xs[ab], xs[ab + 1], xs[ab + 2], xs[ab + 3]};
            uint4 a1r = z4;
            if (q < 2) {
                int ab2 = hp * XS_W + 16 + q * 4;
                a1r.x = xs[ab2]; a1r.y = xs[ab2 + 1]; a1r.z = xs[ab2 + 2]; a1r.w = xs[ab2 + 3];
            }
            bf16x8 a0 = __builtin_bit_cast(bf16x8, a0r);
            bf16x8 a1 = __builtin_bit_cast(bf16x8, a1r);
            int rowb = rg * 16 + 4 * q;
            #pragma unroll
            for (int nt = 0; nt < 6; ++nt) {
                bf16x8 b0 = __builtin_bit_cast(bf16x8, Bpw[(size_t)((6 + nt) << 6) + lane]);
                bf16x8 b1 = __builtin_bit_cast(bf16x8, Bpw[(size_t)((18 + nt) << 6) + lane]);
                f32x4 z = {0.f, 0.f, 0.f, 0.f};
                f32x4 c = __builtin_amdgcn_mfma_f32_16x16x32_bf16(a1, b1, z, 0, 0, 0);
                c = __builtin_amdgcn_mfma_f32_16x16x32_bf16(a0, b0, c, 0, 0, 0);
                #pragma unroll
                for (int r = 0; r < 4; ++r)
                    st_bf_hi(&hsw[(rowb + r) * HS_W + nt * 16 + i16], c[r]);
            }
        }
        if (wy >= 1 && wy <= 6) {                 // rg8, one nt-tile per wave
            int hp = 128 + i16;
            int ab = hp * XS_W + q * 4;
            uint4 a0r = {xs[ab], xs[ab + 1], xs[ab + 2], xs[ab + 3]};
            uint4 a1r = z4;
            if (q < 2) {
                int ab2 = hp * XS_W + 16 + q * 4;
                a1r.x = xs[ab2]; a1r.y = xs[ab2 + 1]; a1r.z = xs[ab2 + 2]; a1r.w = xs[ab2 + 3];
            }
            bf16x8 a0 = __builtin_bit_cast(bf16x8, a0r);
            bf16x8 a1 = __builtin_bit_cast(bf16x8, a1r);
            int rowb = 128 + 4 * q;
            int nt = wy - 1;
            bf16x8 b0 = __builtin_bit_cast(bf16x8, Bpw[(size_t)((6 + nt) << 6) + lane]);
            bf16x8 b1 = __builtin_bit_cast(bf16x8, Bpw[(size_t)((18 + nt) << 6) + lane]);
            f32x4 z = {0.f, 0.f, 0.f, 0.f};
            f32x4 c = __builtin_amdgcn_mfma_f32_16x16x32_bf16(a1, b1, z, 0, 0, 0);
            c = __builtin_amdgcn_mfma_f32_16x16x32_bf16(a0, b0, c, 0, 0, 0);
            #pragma unroll
            for (int r = 0; r < 4; ++r)
                st_bf_hi(&hsw[(rowb + r) * HS_W + nt * 16 + i16], c[r]);
        }
    }
    __syncthreads();

    // ---- depthwise c1 -> uf on 10x10 halo (us2p): 24 (cq,half) sub-units over 8 waves ----
    #pragma unroll 1
    for (int it = 0; it < 3; ++it) {
        int su = wy * 3 + it;                  // 0..23
        int cq = su >> 1;                      // wave-uniform
        int hp2 = (su & 1) * 50 + lane;
        if (lane < 50) {
            int py2 = hp2 / 10, px2 = hp2 - py2 * 10;
            f32x2 a2[4];
            #pragma unroll
            for (int c = 0; c < 4; ++c) a2[c] = (f32x2){0.f, 0.f};
            #pragma unroll
            for (int di = 0; di < 3; ++di)
              #pragma unroll
              for (int dj = 0; dj < 3; ++dj) {
                  int rb = ((py2 + di) * 12 + px2 + dj) * HS_W + cq * 8;
                  unsigned pp[4];
                  pp[0] = *(const unsigned*)&hsw[rb];
                  pp[1] = *(const unsigned*)&hsw[rb + 2];
                  pp[2] = *(const unsigned*)&hsw[rb + 4];
                  pp[3] = *(const unsigned*)&hsw[rb + 6];
                  const f32x2* wrow = (const f32x2*)&c1s[(di * 3 + dj) * 96 + cq * 8];
                  #pragma unroll
                  for (int c2 = 0; c2 < 4; ++c2) {
                      f32x2 hv = {bfpair_lo(pp[c2]), bfpair_hi(pp[c2])};
                      a2[c2] += wrow[c2] * hv;         // v_pk_fma_f32
                  }
              }
            int wb = hp2 * US_W + cq * 8;
            *(unsigned*)&us2p[wb]     = pack2bf(a2[0].x, a2[0].y);
            *(unsigned*)&us2p[wb + 2] = pack2bf(a2[1].x, a2[1].y);
            *(unsigned*)&us2p[wb + 4] = pack2bf(a2[2].x, a2[2].y);
            *(unsigned*)&us2p[wb + 6] = pack2bf(a2[3].x, a2[3].y);
        }
    }
    __syncthreads();

    // ========== PASS B: h(dw) on 10x10 halo via MFMA (7 row-groups, 1 per wave) ==========
    if (wy < 7) {
        int rg = wy;
        int hp = rg * 16 + i16;
        bool okp = hp < 100;
        int hy = hp / 10, hx = hp - hy * 10;
        int pos = okp ? ((hy + 1) * 12 + hx + 1) : 0;
        int ab = pos * XS_W + q * 4;
        uint4 a0r = {xs[ab], xs[ab + 1], xs[ab + 2], xs[ab + 3]};
        uint4 a1r = z4;
        if (q < 2) {
            int ab2 = pos * XS_W + 16 + q * 4;
            a1r.x = xs[ab2]; a1r.y = xs[ab2 + 1]; a1r.z = xs[ab2 + 2]; a1r.w = xs[ab2 + 3];
        }
        bf16x8 a0 = __builtin_bit_cast(bf16x8, a0r);
        bf16x8 a1 = __builtin_bit_cast(bf16x8, a1r);
        int rowb = rg * 16 + 4 * q;
        #pragma unroll
        for (int nt = 0; nt < 6; ++nt) {
            bf16x8 b0 = __builtin_bit_cast(bf16x8, Bpw[(size_t)(nt << 6) + lane]);
            bf16x8 b1 = __builtin_bit_cast(bf16x8, Bpw[(size_t)((12 + nt) << 6) + lane]);
            f32x4 z = {0.f, 0.f, 0.f, 0.f};
            f32x4 c = __builtin_amdgcn_mfma_f32_16x16x32_bf16(a1, b1, z, 0, 0, 0);
            c = __builtin_amdgcn_mfma_f32_16x16x32_bf16(a0, b0, c, 0, 0, 0);
            #pragma unroll
            for (int r = 0; r < 4; ++r)
                st_bf_hi(&hsw[(rowb + r) * HS_W + nt * 16 + i16], c[r]);  // rows>=100 harmless
        }
    }
    __syncthreads();

    // ---- depthwise dw -> gelu(x1) for OWN pixel, 12 channels (this wave's half) ----
    f32x2 greg[6];
    {
        int base = q * 24 + wh * 12;
        #pragma unroll
        for (int cc = 0; cc < 6; ++cc) {
            int c0 = base + 2 * cc;
            f32x2 acc = {0.f, 0.f};
            #pragma unroll
            for (int di = 0; di < 3; ++di)
              #pragma unroll
              for (int dj = 0; dj < 3; ++dj) {
                  unsigned pr = *(const unsigned*)&hsw[((pyT + di) * 10 + pxT + dj) * HS_W + c0];
                  f32x2 hv = {bfpair_lo(pr), bfpair_hi(pr)};
                  f32x2 wv = *(const f32x2*)&wls[(di * 3 + dj) * 96 + c0];
                  acc += wv * hv;
              }
            greg[cc].x = gelu(acc.x);
            greg[cc].y = gelu(acc.y);
        }
    }
    // no barrier needed: KBA never writes hsw

    // ========== KBA: permuted-A MFMA, 6 chunks per wave (wave pair splits 12) ==========
    unsigned* cmb = comb_bf + ((size_t)b * HWP + gp) * 48 + q * 12;

    unsigned cvp[6];
    float rr0[6], rr1[6];
    #pragma unroll
    for (int cl = 0; cl < 6; ++cl) {
        int chunk = wh * 6 + cl;
        int c0 = q * 24 + 2 * chunk;
        // issue LDS reads early so they overlap the MFMA cluster
        float u[18];
        #pragma unroll
        for (int i = 0; i < 3; ++i)
          #pragma unroll
          for (int j = 0; j < 3; ++j) {
              unsigned pr = *(const unsigned*)&us2p[((pyT + i) * 10 + pxT + j) * US_W + c0];
              u[i * 3 + j]     = bfpair_lo(pr);
              u[9 + i * 3 + j] = bfpair_hi(pr);
          }
        f32x4 cf[10];
        #pragma unroll
        for (int nt = 0; nt < 10; ++nt) {
            bf16x8 aW = __builtin_bit_cast(bf16x8, BpkA[(size_t)((chunk * 10 + nt) << 6) + lane]);
            f32x4 z = {0.f, 0.f, 0.f, 0.f};
            cf[nt] = __builtin_amdgcn_mfma_f32_16x16x32_bf16(aW, afrag, z, 0, 0, 0);
        }
        // split accumulate chains (2 partials each) to halve dependency depth
        float s0a = cf[4][2], s1a = cf[9][2];
        float s0b = 0.f,      s1b = 0.f;
        #pragma unroll
        for (int m = 0; m < 8; ++m) {
            s0a += cf[m >> 2][m & 3]       * u[m];
            s1a += cf[5 + (m >> 2)][m & 3] * u[m];
        }
        #pragma unroll
        for (int m = 8; m < 16; ++m) {
            s0b += cf[m >> 2][m & 3]       * u[m];
            s1b += cf[5 + (m >> 2)][m & 3] * u[m];
        }
        s0b += cf[4][0] * u[16] + cf[4][1] * u[17];
        s1b += cf[9][0] * u[16] + cf[9][1] * u[17];

        float x20 = (s0a + s0b) + u[4];       // skip-add: center tap == u[4]/u[13]
        float x21 = (s1a + s1b) + u[13];      // (ga1 pre-folded into BpkA)
        float cv0 = greg[cl].x * x20;
        float cv1 = greg[cl].y * x21;
        cvp[cl] = pack2bf(cv0, cv1);
        rr0[cl] = cv0;
        rr1[cl] = cv1;
    }

    // vectorized comb store: cmb + wh*6 is 8B aligned (q*12+wh*6 even)
    {
        unsigned* cb = cmb + wh * 6;
        uint2 s0 = {cvp[0], cvp[1]};
        uint2 s1 = {cvp[2], cvp[3]};
        uint2 s2 = {cvp[4], cvp[5]};
        *(uint2*)&cb[0] = s0;
        *(uint2*)&cb[2] = s1;
        *(uint2*)&cb[4] = s2;
    }

    // deferred pooled reduction: 12 independent 4-step shfl chains (latency overlaps)
    #pragma unroll
    for (int cl = 0; cl < 6; ++cl) {
        #pragma unroll
        for (int s = 1; s < 16; s <<= 1) {
            rr0[cl] += __shfl_xor(rr0[cl], s, 64);
            rr1[cl] += __shfl_xor(rr1[cl], s, 64);
        }
    }
    if (i16 == 0) {
        #pragma unroll
        for (int cl = 0; cl < 6; ++cl) {
            int c0 = q * 24 + 2 * (wh * 6 + cl);
            atomicAdd(&pooled_s[c0], rr0[cl]);
            atomicAdd(&pooled_s[c0 + 1], rr1[cl]);
        }
    }
    __syncthreads();
    if (tid < 96) atomicAdd(&pooled[b * HIDC + tid], pooled_s[tid]);
}

// ---------------- K2: sv (fused) + out = proj1x1( comb * sv ) ----------------
__global__ __launch_bounds__(256) void k_final(
    const unsigned* __restrict__ comb_bf, const float* __restrict__ pooled,
    const float* __restrict__ scaw, const float* __restrict__ scab,
    const float* __restrict__ projw, float* __restrict__ out)
{
    __shared__ float svs[96];
    __shared__ float cs[96][66];
    int tid = threadIdx.x;
    int blk = blockIdx.x;
    int p0 = blk * 64;
    int b = p0 >> 14;
    if (tid < 96) {
        float dot = 0.f;
        const float* pr = pooled + b * 96;
        const float* wr = scaw + tid * 96;
        #pragma unroll 4
        for (int k = 0; k < 96; ++k) dot += wr[k] * pr[k];
        svs[tid] = scab[tid] + dot * (1.0f / (float)HWP);
    }
    __syncthreads();
    for (int idx = tid; idx < 64 * 12; idx += 256) {
        int px = idx / 12, cq = idx - px * 12;
        uint4 v = *(const uint4*)&comb_bf[(size_t)(p0 + px) * 48 + cq * 4];
        int k0 = cq * 8;
        unsigned pp[4] = {v.x, v.y, v.z, v.w};
        #pragma unroll
        for (int j = 0; j < 4; ++j) {
            cs[k0 + 2*j][px]     = bfpair_lo(pp[j]) * svs[k0 + 2*j];
            cs[k0 + 2*j + 1][px] = bfpair_hi(pp[j]) * svs[k0 + 2*j + 1];
        }
    }
    __syncthreads();
    int l = tid & 63, w = tid >> 6;
    int o0 = w * 12;
    float acc[12];
    #pragma unroll
    for (int o = 0; o < 12; ++o) acc[o] = 0.f;
    #pragma unroll 4
    for (int k = 0; k < 96; ++k) {
        float v = cs[k][l];
        #pragma unroll
        for (int o = 0; o < 12; ++o)
            acc[o] += projw[(o0 + o) * 96 + k] * v;      // wave-uniform -> s_loads
    }
    float* ob = out + (size_t)b * DIMC * HWP + (p0 & 16383) + l;
    #pragma unroll
    for (int o = 0; o < 12; ++o)
        ob[(o0 + o) * HWP] = acc[o];
}

extern "C" void kernel_launch(void* const* d_in, const int* in_sizes, int n_in,
                              void* d_out, int out_size, void* d_ws, size_t ws_size,
                              hipStream_t stream)
{
    const float* x     = (const float*)d_in[0];
    const float* dw1w  = (const float*)d_in[1];
    const float* dw2w  = (const float*)d_in[2];
    const float* projw = (const float*)d_in[3];
    const float* scaw  = (const float*)d_in[4];
    const float* scab  = (const float*)d_in[5];
    const float* c1w1  = (const float*)d_in[6];
    const float* c1w2  = (const float*)d_in[7];
    const float* kbaw  = (const float*)d_in[8];
    const float* kbab  = (const float*)d_in[9];
    const float* c2w1  = (const float*)d_in[10];
    const float* c2b1  = (const float*)d_in[11];
    const float* c2w2  = (const float*)d_in[12];
    const float* c2b2  = (const float*)d_in[13];
    const float* c211w = (const float*)d_in[14];
    const float* c211b = (const float*)d_in[15];
    const float* attg  = (const float*)d_in[16];
    const float* ga1   = (const float*)d_in[17];

    unsigned* x_p     = (unsigned*)d_ws;                           // 1,572,864 dw
    unsigned* comb_bf = x_p + (size_t)BB * HWP * 24;               // 3,145,728 dw
    float* pooled     = (float*)(comb_bf + (size_t)BB * HWP * 48); // 384 f
    unsigned short* BpkA = (unsigned short*)(pooled + BB * HIDC);  // 61,440 ush
    unsigned short* Bpw  = BpkA + 61440;                           // 12,288 ush
    unsigned short* Aps  = Bpw + 12288;                            //  2,048 ush
    unsigned short* Ag   = Aps + 2048;                             //  1,024 ush

    k_prep <<<556,  256, 0, stream>>>(x, kbaw, kbab, dw1w, c1w1, ga1, c211w, c2w2, c2b2,
                                      c211b, attg, BpkA, Bpw, Aps, Ag, x_p, pooled);
    k_mff  <<<1024, dim3(64,8,1), 0, stream>>>(x_p, (const uint4*)BpkA, (const uint4*)Bpw,
                                               (const uint4*)Aps, (const uint4*)Ag,
                                               c1w2, dw2w, c2w1, c2b1, comb_bf, pooled);
    k_final<<<1024, 256, 0, stream>>>(comb_bf, pooled, scaw, scab, projw, (float*)d_out);
}

// Round 7
// 194.687 us; speedup vs baseline: 1.0937x; 1.0002x over previous
//
#include <hip/hip_runtime.h>
#include <math.h>

#define BB 4
#define HH 128
#define WW 128
#define HWP (HH*WW)
#define DIMC 48
#define HIDC 96
#define NSETC 32

// Odd-dword LDS row strides (bank-conflict fix):
#define XS_W 27     // xs row stride in dwords
#define HS_W 102    // hsw row stride in ushorts = 51 dwords
#define US_W 102    // us2p row stride in ushorts = 51 dwords

typedef __attribute__((ext_vector_type(8))) short bf16x8;
typedef __attribute__((ext_vector_type(4))) float f32x4;
typedef __attribute__((ext_vector_type(2))) float f32x2;

static __device__ __forceinline__ unsigned short f2bf(float f) {   // RNE (pack path, cold)
    union { float f; unsigned u; } v; v.f = f;
    unsigned r = (v.u + 0x7FFFu + ((v.u >> 16) & 1u)) >> 16;
    return (unsigned short)r;
}
static __device__ __forceinline__ unsigned rnd_bf(float f) {       // +0x8000 round-half-up
    union { float f; unsigned u; } v; v.f = f;
    return v.u + 0x8000u;
}
static __device__ __forceinline__ unsigned pack2bf(float lo, float hi) {
    return __builtin_amdgcn_perm(rnd_bf(hi), rnd_bf(lo), 0x07060302u);
}
static __device__ __forceinline__ void st_bf_hi(unsigned short* p, float f) {
    *p = (unsigned short)(rnd_bf(f) >> 16);
}
static __device__ __forceinline__ float bfpair_lo(unsigned pr) {
    union { unsigned u; float f; } v; v.u = pr << 16; return v.f;
}
static __device__ __forceinline__ float bfpair_hi(unsigned pr) {
    union { unsigned u; float f; } v; v.u = pr & 0xffff0000u; return v.f;
}
// Branchless gelu via A&S 7.1.26 erf approx (|erf err| <= ~3e-7 incl rcp/exp ulps).
// comb is quantized to bf16 downstream (rel 2^-9), so this is precision-free headroom.
// ~16 VALU vs OCML erff's ~25-30 with divergent region split.
static __device__ __forceinline__ float gelu_fast(float xv) {
    float z = fabsf(xv) * 0.70710678118654752f;          // |x|/sqrt(2)
    float t = __builtin_amdgcn_rcpf(fmaf(0.3275911f, z, 1.0f));
    float e = __builtin_amdgcn_exp2f(z * z * -1.4426950408889634f);  // exp(-z^2)
    float p = fmaf(1.061405429f, t, -1.453152027f);
    p = fmaf(p, t, 1.421413741f);
    p = fmaf(p, t, -0.284496736f);
    p = fmaf(p, t, 0.254829592f);
    p = p * t;                                           // E/e
    float s = 0.5f * xv * (p * e);                       // 0.5 x E
    return xv >= 0.f ? xv - s : s;                       // 0.5x(1+erf(x/s2))
}

// ---------------- K0: weight pack (permuted A-operand layouts) + x transpose ----------------
__global__ __launch_bounds__(256) void k_prep(
    const float* __restrict__ x,
    const float* __restrict__ kbaw, const float* __restrict__ kbab,
    const float* __restrict__ dw1w, const float* __restrict__ c1w1,
    const float* __restrict__ ga1,  const float* __restrict__ c211w,
    const float* __restrict__ c2w2, const float* __restrict__ c2b2,
    const float* __restrict__ c211b, const float* __restrict__ attg,
    unsigned short* __restrict__ Bpk, unsigned short* __restrict__ Bpw,
    unsigned short* __restrict__ Aps, unsigned short* __restrict__ Ag,
    unsigned* __restrict__ x_p, float* __restrict__ pooled)
{
    __shared__ unsigned ts[256 * 26];
    int blk = blockIdx.x, tid = threadIdx.x;
    if (blk < 300) {
        int t = blk * 256 + tid;
        if (t < 61440) {                         // BpkA
            int j = t & 7, lane = (t >> 3) & 63, tile = t >> 9;
            int chunk = tile / 10, nt = tile - chunk * 10;
            int m = lane & 15, qn = lane >> 4;
            int lc = 4 * nt + (m & 3);           // local col within this q's 40-block
            int o = lc / 20, tt = lc % 20;
            int c = (m >> 2) * 24 + 2 * chunk + o;
            int n = qn * 8 + j;
            float v = 0.f;
            if (tt < 18)       v = kbaw[n * 1728 + (c >> 1) * 36 + (c & 1) * 18 + tt] * ga1[c];
            else if (tt == 18) v = kbab[n * 96 + c] * ga1[c];
            Bpk[t] = f2bf(v);
        } else if (t < 73728) {                  // Bpw (B operand)
            int u = t - 61440;
            int s = u / 6144;
            int rem = u % 6144;
            int nt = rem >> 9;
            int lane = (rem >> 3) & 63, j = rem & 7;
            int k = s * 32 + ((lane >> 4) << 3) + j;
            int col = (nt << 4) + (lane & 15);
            float v = 0.f;
            if (k < 48) v = (col < 96) ? dw1w[col * 48 + k] : c1w1[(col - 96) * 48 + k];
            Bpw[u] = f2bf(v);
        } else if (t < 75776) {                  // Aps (skip 1x1 A-operand)
            int u = t - 73728;
            int j = u & 7, lane = (u >> 3) & 63, tile = u >> 9;   // 0..3 = kt*2+nt2
            int kt = tile >> 1, nt2 = tile & 1;
            int m = lane & 15, qn = lane >> 4;
            int n = 8 * (m >> 2) + 4 * nt2 + (m & 3);
            int k = kt * 32 + qn * 8 + j;
            Aps[u] = f2bf(k < 48 ? c211w[n * 48 + k] : 0.f);
        } else if (t < 76800) {                  // Ag (gate 1x1 A-operand, biases at k=12)
            int u = t - 75776;
            int j = u & 7, lane = (u >> 3) & 63, nt2 = u >> 9;    // 0..1
            int m = lane & 15, qn = lane >> 4;
            int n = 8 * (m >> 2) + 4 * nt2 + (m & 3);
            int k = qn * 8 + j;
            float v = 0.f;
            if (k < 12)       v = c2w2[n * 12 + k] * attg[n];
            else if (k == 12) v = c2b2[n] * attg[n] + c211b[n];
            Ag[u] = f2bf(v);
        }
    } else {
        int xblk = blk - 300;
        if (xblk == 0) {
            for (int i = tid; i < BB * HIDC; i += 256) pooled[i] = 0.f;
        }
        int b = xblk >> 6;
        int p0 = (xblk & 63) << 8;
        const float* xb = x + (size_t)b * DIMC * HWP + p0;
        #pragma unroll
        for (int c2 = 0; c2 < 24; ++c2) {
            float lo = xb[(2 * c2) * HWP + tid];
            float hi = xb[(2 * c2 + 1) * HWP + tid];
            ts[tid * 26 + c2] = pack2bf(lo, hi);
        }
        __syncthreads();
        unsigned* dst = x_p + ((size_t)b * HWP + p0) * 24;
        for (int idx = tid; idx < 256 * 24; idx += 256) {
            int px = idx / 24, j2 = idx - px * 24;
            dst[px * 24 + j2] = ts[px * 26 + j2];
        }
    }
}

// ---------------- K1 (mega-fused): att + 1x1 MFMA + depthwise + KBA -> comb(bf16) ----------------
// 1024 blocks, dim3(64,8); 2 blocks/CU (LDS ~72.7 KB) -> 4 waves/SIMD.
// Round-7: (1) erff gelu -> branchless A&S poly (~150 VALU/thread saved; comb is bf16 so
// the ~3e-7 erf error is below quantization). (2) dw-gelu phase fused INTO the KBA chunk
// loop: each chunk computes its own channel pair's depthwise+gelu, hiding that VALU+LDS
// under the 10 in-flight BpkA L2 loads; frees the greg[12] register array.
__global__ __launch_bounds__(512, 2) void k_mff(
    const unsigned* __restrict__ x_p,
    const uint4* __restrict__ BpkA, const uint4* __restrict__ Bpw,
    const uint4* __restrict__ Aps,  const uint4* __restrict__ Ag,
    const float* __restrict__ c1w2, const float* __restrict__ dw2w,
    const float* __restrict__ c2w1, const float* __restrict__ c2b1,
    unsigned* __restrict__ comb_bf, float* __restrict__ pooled)
{
    __shared__ __attribute__((aligned(16))) unsigned xs[144 * XS_W];        // x halo 12x12 (15.2 KB)
    __shared__ __attribute__((aligned(16))) unsigned short hsw[144 * HS_W]; // h tiles (28.7 KB)
    __shared__ __attribute__((aligned(16))) unsigned short us2p[100 * US_W];// uf halo ; aliased att_t (19.9 KB)
    __shared__ __attribute__((aligned(16))) float wls[864 + 432 + 24];      // dw2w | c2w1 | c2b1 (5.3 KB)
    __shared__ __attribute__((aligned(16))) float c1s[864];                 // c1w2 relayout [tap][96] (3.5 KB)
    __shared__ float pooled_s[96];

    int lane = threadIdx.x, wy = threadIdx.y;   // wy 0..7
    int tid = wy * 64 + lane;
    int blk = blockIdx.x;
    int b = blk >> 8, ty = (blk >> 4) & 15, tx = blk & 15;
    int q = lane >> 4, i16 = lane & 15;
    int wh = wy >> 2;          // channel/chunk half (0/1)
    int wp = wy & 3;           // pixel group 0..3

    float* wats  = wls + 864;    // [g][tap][2]
    float* c2b1s = wls + 864 + 432;
    float* att_tf = (float*)us2p; // [px(64)][XS_W] floats; us2p fully rewritten later by dwc1

    // ---- stage: xs / weight tables / pooled_s ----
    if (tid < 96) pooled_s[tid] = 0.f;
    for (int idx = tid; idx < 864; idx += 512) {
        int t5 = idx / 96, c = idx - t5 * 96;
        wls[idx] = dw2w[c * 9 + t5];
        c1s[idx] = c1w2[c * 9 + t5];
    }
    for (int idx = tid; idx < 216; idx += 512) {
        int g = idx / 9, tap = idx - g * 9;
        wats[idx * 2]     = c2w1[g * 18 + tap];
        wats[idx * 2 + 1] = c2w1[g * 18 + 9 + tap];
    }
    if (tid < 24) c2b1s[tid] = c2b1[tid];
    for (int idx = tid; idx < 144 * 12; idx += 512) {
        int pos = idx / 12, jp = idx - pos * 12;
        int gy = ty * 8 - 2 + pos / 12, gx = tx * 8 - 2 + pos % 12;
        uint2 v = {0u, 0u};
        if (((unsigned)gy < (unsigned)HH) & ((unsigned)gx < (unsigned)WW))
            v = *(const uint2*)&x_p[((size_t)b * HWP + gy * WW + gx) * 24 + jp * 2];
        xs[pos * XS_W + jp * 2]     = v.x;
        xs[pos * XS_W + jp * 2 + 1] = v.y;
    }
    __syncthreads();

    int p_t = wp * 16 + i16;
    int pyT = p_t >> 3, pxT = p_t & 7;
    int gp = (ty * 8 + pyT) * WW + tx * 8 + pxT;
    uint4 z4 = {0u, 0u, 0u, 0u};

    // ---- att: grouped conv t (8 threads/pixel across wave pair, 3 groups each) ----
    #pragma unroll
    for (int ci = 0; ci < 3; ++ci) {
        int g = q * 6 + wh * 3 + ci;
        f32x2 av = {0.f, 0.f};
        #pragma unroll
        for (int di = 0; di < 3; ++di)
          #pragma unroll
          for (int dj = 0; dj < 3; ++dj) {
              unsigned pr = xs[((pyT + 1 + di) * 12 + pxT + 1 + dj) * XS_W + g];
              f32x2 w2 = *(const f32x2*)&wats[(g * 9 + di * 3 + dj) * 2];
              f32x2 hv = {bfpair_lo(pr), bfpair_hi(pr)};
              av += w2 * hv;                       // v_pk_fma_f32
          }
        att_tf[p_t * XS_W + g] = c2b1s[g] + av.x + av.y;
    }
    __syncthreads();

    // ---- att: gate + skip via permuted-A MFMA -> afrag in registers ----
    bf16x8 afrag;
    {
        int p26 = p_t * XS_W;
        unsigned tgd[4];
        #pragma unroll
        for (int i2 = 0; i2 < 4; ++i2) {
            int k0 = q * 8 + 2 * i2;
            int k1 = k0 + 1;
            float v0 = (k0 < 12) ? att_tf[p26 + k0] * att_tf[p26 + 12 + k0] : (k0 == 12 ? 1.f : 0.f);
            float v1 = (k1 < 12) ? att_tf[p26 + k1] * att_tf[p26 + 12 + k1] : (k1 == 12 ? 1.f : 0.f);
            tgd[i2] = pack2bf(v0, v1);
        }
        uint4 tgr = {tgd[0], tgd[1], tgd[2], tgd[3]};
        bf16x8 btg = __builtin_bit_cast(bf16x8, tgr);

        int cen = (pyT + 2) * 12 + (pxT + 2);
        int cb = cen * XS_W + q * 4;
        uint4 bx0r = {xs[cb], xs[cb + 1], xs[cb + 2], xs[cb + 3]};
        uint4 bx1r = z4;                // MUST be zeroed for q>=2: xs entries 24+ are
        if (q < 2) {                    // unwritten garbage; 0-weight x NaN = NaN
            int cb2 = cen * XS_W + 16 + q * 4;
            bx1r.x = xs[cb2]; bx1r.y = xs[cb2 + 1]; bx1r.z = xs[cb2 + 2]; bx1r.w = xs[cb2 + 3];
        }
        bf16x8 bx0 = __builtin_bit_cast(bf16x8, bx0r);
        bf16x8 bx1 = __builtin_bit_cast(bf16x8, bx1r);

        float attv[8];
        #pragma unroll
        for (int nt2 = 0; nt2 < 2; ++nt2) {
            bf16x8 ag  = __builtin_bit_cast(bf16x8, Ag[nt2 * 64 + lane]);
            bf16x8 as0 = __builtin_bit_cast(bf16x8, Aps[nt2 * 64 + lane]);
            bf16x8 as1 = __builtin_bit_cast(bf16x8, Aps[(2 + nt2) * 64 + lane]);
            f32x4 z = {0.f, 0.f, 0.f, 0.f};
            f32x4 c = __builtin_amdgcn_mfma_f32_16x16x32_bf16(ag, btg, z, 0, 0, 0);
            c = __builtin_amdgcn_mfma_f32_16x16x32_bf16(as1, bx1, c, 0, 0, 0);
            c = __builtin_amdgcn_mfma_f32_16x16x32_bf16(as0, bx0, c, 0, 0, 0);
            #pragma unroll
            for (int r = 0; r < 4; ++r) attv[nt2 * 4 + r] = c[r];
        }
        uint4 au = {pack2bf(attv[0], attv[1]), pack2bf(attv[2], attv[3]),
                    pack2bf(attv[4], attv[5]), pack2bf(attv[6], attv[7])};
        afrag = __builtin_bit_cast(bf16x8, au);
    }
    // NO barrier: att_tf lives in us2p; PASS A touches only hsw/xs. The next us2p
    // write (dwc1) is behind the PASS A -> dwc1 barrier.

    // ========== PASS A: h(c1) on 12x12 halo via MFMA ==========
    // Each wave: own rg (6 nt). rg8's 6 nt-tiles spread one-each over waves 1..6.
    {
        {
            int rg = wy;
            int hp = rg * 16 + i16;
            int ab = hp * XS_W + q * 4;
            uint4 a0r = {xs[ab], xs[ab + 1], xs[ab + 2], xs[ab + 3]};
            uint4 a1r = z4;
            if (q < 2) {
                int ab2 = hp * XS_W + 16 + q * 4;
                a1r.x = xs[ab2]; a1r.y = xs[ab2 + 1]; a1r.z = xs[ab2 + 2]; a1r.w = xs[ab2 + 3];
            }
            bf16x8 a0 = __builtin_bit_cast(bf16x8, a0r);
            bf16x8 a1 = __builtin_bit_cast(bf16x8, a1r);
            int rowb = rg * 16 + 4 * q;
            #pragma unroll
            for (int nt = 0; nt < 6; ++nt) {
                bf16x8 b0 = __builtin_bit_cast(bf16x8, Bpw[(size_t)((6 + nt) << 6) + lane]);
                bf16x8 b1 = __builtin_bit_cast(bf16x8, Bpw[(size_t)((18 + nt) << 6) + lane]);
                f32x4 z = {0.f, 0.f, 0.f, 0.f};
                f32x4 c = __builtin_amdgcn_mfma_f32_16x16x32_bf16(a1, b1, z, 0, 0, 0);
                c = __builtin_amdgcn_mfma_f32_16x16x32_bf16(a0, b0, c, 0, 0, 0);
                #pragma unroll
                for (int r = 0; r < 4; ++r)
                    st_bf_hi(&hsw[(rowb + r) * HS_W + nt * 16 + i16], c[r]);
            }
        }
        if (wy >= 1 && wy <= 6) {                 // rg8, one nt-tile per wave
            int hp = 128 + i16;
            int ab = hp * XS_W + q * 4;
            uint4 a0r = {xs[ab], xs[ab + 1], xs[ab + 2], xs[ab + 3]};
            uint4 a1r = z4;
            if (q < 2) {
                int ab2 = hp * XS_W + 16 + q * 4;
                a1r.x = xs[ab2]; a1r.y = xs[ab2 + 1]; a1r.z = xs[ab2 + 2]; a1r.w = xs[ab2 + 3];
            }
            bf16x8 a0 = __builtin_bit_cast(bf16x8, a0r);
            bf16x8 a1 = __builtin_bit_cast(bf16x8, a1r);
            int rowb = 128 + 4 * q;
            int nt = wy - 1;
            bf16x8 b0 = __builtin_bit_cast(bf16x8, Bpw[(size_t)((6 + nt) << 6) + lane]);
            bf16x8 b1 = __builtin_bit_cast(bf16x8, Bpw[(size_t)((18 + nt) << 6) + lane]);
            f32x4 z = {0.f, 0.f, 0.f, 0.f};
            f32x4 c = __builtin_amdgcn_mfma_f32_16x16x32_bf16(a1, b1, z, 0, 0, 0);
            c = __builtin_amdgcn_mfma_f32_16x16x32_bf16(a0, b0, c, 0, 0, 0);
            #pragma unroll
            for (int r = 0; r < 4; ++r)
                st_bf_hi(&hsw[(rowb + r) * HS_W + nt * 16 + i16], c[r]);
        }
    }
    __syncthreads();

    // ---- depthwise c1 -> uf on 10x10 halo (us2p): 24 (cq,half) sub-units over 8 waves ----
    #pragma unroll 1
    for (int it = 0; it < 3; ++it) {
        int su = wy * 3 + it;                  // 0..23
        int cq = su >> 1;                      // wave-uniform
        int hp2 = (su & 1) * 50 + lane;
        if (lane < 50) {
            int py2 = hp2 / 10, px2 = hp2 - py2 * 10;
            f32x2 a2[4];
            #pragma unroll
            for (int c = 0; c < 4; ++c) a2[c] = (f32x2){0.f, 0.f};
            #pragma unroll
            for (int di = 0; di < 3; ++di)
              #pragma unroll
              for (int dj = 0; dj < 3; ++dj) {
                  int rb = ((py2 + di) * 12 + px2 + dj) * HS_W + cq * 8;
                  unsigned pp[4];
                  pp[0] = *(const unsigned*)&hsw[rb];
                  pp[1] = *(const unsigned*)&hsw[rb + 2];
                  pp[2] = *(const unsigned*)&hsw[rb + 4];
                  pp[3] = *(const unsigned*)&hsw[rb + 6];
                  const f32x2* wrow = (const f32x2*)&c1s[(di * 3 + dj) * 96 + cq * 8];
                  #pragma unroll
                  for (int c2 = 0; c2 < 4; ++c2) {
                      f32x2 hv = {bfpair_lo(pp[c2]), bfpair_hi(pp[c2])};
                      a2[c2] += wrow[c2] * hv;         // v_pk_fma_f32
                  }
              }
            int wb = hp2 * US_W + cq * 8;
            *(unsigned*)&us2p[wb]     = pack2bf(a2[0].x, a2[0].y);
            *(unsigned*)&us2p[wb + 2] = pack2bf(a2[1].x, a2[1].y);
            *(unsigned*)&us2p[wb + 4] = pack2bf(a2[2].x, a2[2].y);
            *(unsigned*)&us2p[wb + 6] = pack2bf(a2[3].x, a2[3].y);
        }
    }
    __syncthreads();

    // ========== PASS B: h(dw) on 10x10 halo via MFMA (7 row-groups, 1 per wave) ==========
    if (wy < 7) {
        int rg = wy;
        int hp = rg * 16 + i16;
        bool okp = hp < 100;
        int hy = hp / 10, hx = hp - hy * 10;
        int pos = okp ? ((hy + 1) * 12 + hx + 1) : 0;
        int ab = pos * XS_W + q * 4;
        uint4 a0r = {xs[ab], xs[ab + 1], xs[ab + 2], xs[ab + 3]};
        uint4 a1r = z4;
        if (q < 2) {
            int ab2 = pos * XS_W + 16 + q * 4;
            a1r.x = xs[ab2]; a1r.y = xs[ab2 + 1]; a1r.z = xs[ab2 + 2]; a1r.w = xs[ab2 + 3];
        }
        bf16x8 a0 = __builtin_bit_cast(bf16x8, a0r);
        bf16x8 a1 = __builtin_bit_cast(bf16x8, a1r);
        int rowb = rg * 16 + 4 * q;
        #pragma unroll
        for (int nt = 0; nt < 6; ++nt) {
            bf16x8 b0 = __builtin_bit_cast(bf16x8, Bpw[(size_t)(nt << 6) + lane]);
            bf16x8 b1 = __builtin_bit_cast(bf16x8, Bpw[(size_t)((12 + nt) << 6) + lane]);
            f32x4 z = {0.f, 0.f, 0.f, 0.f};
            f32x4 c = __builtin_amdgcn_mfma_f32_16x16x32_bf16(a1, b1, z, 0, 0, 0);
            c = __builtin_amdgcn_mfma_f32_16x16x32_bf16(a0, b0, c, 0, 0, 0);
            #pragma unroll
            for (int r = 0; r < 4; ++r)
                st_bf_hi(&hsw[(rowb + r) * HS_W + nt * 16 + i16], c[r]);  // rows>=100 harmless
        }
    }
    __syncthreads();

    // ========== fused dw-gelu + KBA: per chunk, gelu for its channel pair hides ==========
    // ========== under the 10 BpkA L2 loads; hsw/us2p both stable (no writes) ==========
    unsigned* cmb = comb_bf + ((size_t)b * HWP + gp) * 48 + q * 12;

    unsigned cvp[6];
    float rr0[6], rr1[6];
    #pragma unroll
    for (int cl = 0; cl < 6; ++cl) {
        int chunk = wh * 6 + cl;
        int c0 = q * 24 + 2 * chunk;         // == (q*24 + wh*12) + 2*cl

        // depthwise dw conv + gelu for this chunk's channel pair (overlaps BpkA latency)
        f32x2 dacc = {0.f, 0.f};
        #pragma unroll
        for (int di = 0; di < 3; ++di)
          #pragma unroll
          for (int dj = 0; dj < 3; ++dj) {
              unsigned pr = *(const unsigned*)&hsw[((pyT + di) * 10 + pxT + dj) * HS_W + c0];
              f32x2 hv = {bfpair_lo(pr), bfpair_hi(pr)};
              f32x2 wv = *(const f32x2*)&wls[(di * 3 + dj) * 96 + c0];
              dacc += wv * hv;
          }
        float g0 = gelu_fast(dacc.x);
        float g1 = gelu_fast(dacc.y);

        // uf taps from us2p
        float u[18];
        #pragma unroll
        for (int i = 0; i < 3; ++i)
          #pragma unroll
          for (int j = 0; j < 3; ++j) {
              unsigned pr = *(const unsigned*)&us2p[((pyT + i) * 10 + pxT + j) * US_W + c0];
              u[i * 3 + j]     = bfpair_lo(pr);
              u[9 + i * 3 + j] = bfpair_hi(pr);
          }
        f32x4 cf[10];
        #pragma unroll
        for (int nt = 0; nt < 10; ++nt) {
            bf16x8 aW = __builtin_bit_cast(bf16x8, BpkA[(size_t)((chunk * 10 + nt) << 6) + lane]);
            f32x4 z = {0.f, 0.f, 0.f, 0.f};
            cf[nt] = __builtin_amdgcn_mfma_f32_16x16x32_bf16(aW, afrag, z, 0, 0, 0);
        }
        // split accumulate chains (2 partials each) to halve dependency depth
        float s0a = cf[4][2], s1a = cf[9][2];
        float s0b = 0.f,      s1b = 0.f;
        #pragma unroll
        for (int m = 0; m < 8; ++m) {
            s0a += cf[m >> 2][m & 3]       * u[m];
            s1a += cf[5 + (m >> 2)][m & 3] * u[m];
        }
        #pragma unroll
        for (int m = 8; m < 16; ++m) {
            s0b += cf[m >> 2][m & 3]       * u[m];
            s1b += cf[5 + (m >> 2)][m & 3] * u[m];
        }
        s0b += cf[4][0] * u[16] + cf[4][1] * u[17];
        s1b += cf[9][0] * u[16] + cf[9][1] * u[17];

        float x20 = (s0a + s0b) + u[4];       // skip-add: center tap == u[4]/u[13]
        float x21 = (s1a + s1b) + u[13];      // (ga1 pre-folded into BpkA)
        float cv0 = g0 * x20;
        float cv1 = g1 * x21;
        cvp[cl] = pack2bf(cv0, cv1);
        rr0[cl] = cv0;
        rr1[cl] = cv1;
    }

    // vectorized comb store: cmb + wh*6 is 8B aligned (q*12+wh*6 even)
    {
        unsigned* cb = cmb + wh * 6;
        uint2 s0 = {cvp[0], cvp[1]};
        uint2 s1 = {cvp[2], cvp[3]};
        uint2 s2 = {cvp[4], cvp[5]};
        *(uint2*)&cb[0] = s0;
        *(uint2*)&cb[2] = s1;
        *(uint2*)&cb[4] = s2;
    }

    // deferred pooled reduction: 12 independent 4-step shfl chains (latency overlaps)
    #pragma unroll
    for (int cl = 0; cl < 6; ++cl) {
        #pragma unroll
        for (int s = 1; s < 16; s <<= 1) {
            rr0[cl] += __shfl_xor(rr0[cl], s, 64);
            rr1[cl] += __shfl_xor(rr1[cl], s, 64);
        }
    }
    if (i16 == 0) {
        #pragma unroll
        for (int cl = 0; cl < 6; ++cl) {
            int c0 = q * 24 + 2 * (wh * 6 + cl);
            atomicAdd(&pooled_s[c0], rr0[cl]);
            atomicAdd(&pooled_s[c0 + 1], rr1[cl]);
        }
    }
    __syncthreads();
    if (tid < 96) atomicAdd(&pooled[b * HIDC + tid], pooled_s[tid]);
}

// ---------------- K2: sv (fused) + out = proj1x1( comb * sv ) ----------------
__global__ __launch_bounds__(256) void k_final(
    const unsigned* __restrict__ comb_bf, const float* __restrict__ pooled,
    const float* __restrict__ scaw, const float* __restrict__ scab,
    const float* __restrict__ projw, float* __restrict__ out)
{
    __shared__ float svs[96];
    __shared__ float cs[96][66];
    int tid = threadIdx.x;
    int blk = blockIdx.x;
    int p0 = blk * 64;
    int b = p0 >> 14;
    if (tid < 96) {
        float dot = 0.f;
        const float* pr = pooled + b * 96;
        const float* wr = scaw + tid * 96;
        #pragma unroll 4
        for (int k = 0; k < 96; ++k) dot += wr[k] * pr[k];
        svs[tid] = scab[tid] + dot * (1.0f / (float)HWP);
    }
    __syncthreads();
    for (int idx = tid; idx < 64 * 12; idx += 256) {
        int px = idx / 12, cq = idx - px * 12;
        uint4 v = *(const uint4*)&comb_bf[(size_t)(p0 + px) * 48 + cq * 4];
        int k0 = cq * 8;
        unsigned pp[4] = {v.x, v.y, v.z, v.w};
        #pragma unroll
        for (int j = 0; j < 4; ++j) {
            cs[k0 + 2*j][px]     = bfpair_lo(pp[j]) * svs[k0 + 2*j];
            cs[k0 + 2*j + 1][px] = bfpair_hi(pp[j]) * svs[k0 + 2*j + 1];
        }
    }
    __syncthreads();
    int l = tid & 63, w = tid >> 6;
    int o0 = w * 12;
    float acc[12];
    #pragma unroll
    for (int o = 0; o < 12; ++o) acc[o] = 0.f;
    #pragma unroll 4
    for (int k = 0; k < 96; ++k) {
        float v = cs[k][l];
        #pragma unroll
        for (int o = 0; o < 12; ++o)
            acc[o] += projw[(o0 + o) * 96 + k] * v;      // wave-uniform -> s_loads
    }
    float* ob = out + (size_t)b * DIMC * HWP + (p0 & 16383) + l;
    #pragma unroll
    for (int o = 0; o < 12; ++o)
        ob[(o0 + o) * HWP] = acc[o];
}

extern "C" void kernel_launch(void* const* d_in, const int* in_sizes, int n_in,
                              void* d_out, int out_size, void* d_ws, size_t ws_size,
                              hipStream_t stream)
{
    const float* x     = (const float*)d_in[0];
    const float* dw1w  = (const float*)d_in[1];
    const float* dw2w  = (const float*)d_in[2];
    const float* projw = (const float*)d_in[3];
    const float* scaw  = (const float*)d_in[4];
    const float* scab  = (const float*)d_in[5];
    const float* c1w1  = (const float*)d_in[6];
    const float* c1w2  = (const float*)d_in[7];
    const float* kbaw  = (const float*)d_in[8];
    const float* kbab  = (const float*)d_in[9];
    const float* c2w1  = (const float*)d_in[10];
    const float* c2b1  = (const float*)d_in[11];
    const float* c2w2  = (const float*)d_in[12];
    const float* c2b2  = (const float*)d_in[13];
    const float* c211w = (const float*)d_in[14];
    const float* c211b = (const float*)d_in[15];
    const float* attg  = (const float*)d_in[16];
    const float* ga1   = (const float*)d_in[17];

    unsigned* x_p     = (unsigned*)d_ws;                           // 1,572,864 dw
    unsigned* comb_bf = x_p + (size_t)BB * HWP * 24;               // 3,145,728 dw
    float* pooled     = (float*)(comb_bf + (size_t)BB * HWP * 48); // 384 f
    unsigned short* BpkA = (unsigned short*)(pooled + BB * HIDC);  // 61,440 ush
    unsigned short* Bpw  = BpkA + 61440;                           // 12,288 ush
    unsigned short* Aps  = Bpw + 12288;                            //  2,048 ush
    unsigned short* Ag   = Aps + 2048;                             //  1,024 ush

    k_prep <<<556,  256, 0, stream>>>(x, kbaw, kbab, dw1w, c1w1, ga1, c211w, c2w2, c2b2,
                                      c211b, attg, BpkA, Bpw, Aps, Ag, x_p, pooled);
    k_mff  <<<1024, dim3(64,8,1), 0, stream>>>(x_p, (const uint4*)BpkA, (const uint4*)Bpw,
                                               (const uint4*)Aps, (const uint4*)Ag,
                                               c1w2, dw2w, c2w1, c2b1, comb_bf, pooled);
    k_final<<<1024, 256, 0, stream>>>(comb_bf, pooled, scaw, scab, projw, (float*)d_out);
}